// Round 1
// 261.214 us; speedup vs baseline: 1.0042x; 1.0042x over previous
//
#include <hip/hip_runtime.h>
#include <hip/hip_bf16.h>
#include <stdint.h>

// Problem constants
#define BB   2
#define SS   2048
#define HH   768
#define NHH  12
#define HDD  64
#define BSS  (BB*SS)          // 4096 rows
#define NBH  (BB*NHH)         // 24
#define ROWS_BH (NBH*SS)      // 49152
#define NSPLIT 2

typedef unsigned short u16;
typedef unsigned int   u32;
typedef __attribute__((ext_vector_type(8))) short bf16x8_t;   // 8 bf16 (4 VGPRs) - MFMA A/B frag
typedef __attribute__((ext_vector_type(4))) float f32x4;      // MFMA C/D frag
typedef __attribute__((ext_vector_type(2))) u32   u32x2;
typedef __attribute__((ext_vector_type(4))) u32   u32x4;

#define MFMA16(a, b, c) __builtin_amdgcn_mfma_f32_16x16x32_bf16((a), (b), (c), 0, 0, 0)

__device__ __forceinline__ float b2f(u16 u) {
    u32 x = ((u32)u) << 16; float f; __builtin_memcpy(&f, &x, 4); return f;
}
__device__ __forceinline__ u16 f2b(float f) {   // round-to-nearest-even bf16
    u32 x; __builtin_memcpy(&x, &f, 4);
    u32 r = x + 0x7fffu + ((x >> 16) & 1u);
    return (u16)(r >> 16);
}
// async global->LDS 16B DMA (m97 pattern; LDS dest = wave base + lane*16)
__device__ __forceinline__ void async16(const u16* g, u16* l) {
    __builtin_amdgcn_global_load_lds(
        (const __attribute__((address_space(1))) void*)g,
        (__attribute__((address_space(3))) void*)l, 16, 0, 0);
}

// ---------------------------------------------------------------------------
// Kernel 1 (fused prep): blockIdx.x ranges select role.
//   [0,576)      : transpose fp32 768x768 weights -> bf16 Wt[n][k]
//   [576,2624)   : LayerNorm(hidden)->xln (y=0) / cross fp32->bf16 (y=1)
//   [2624,3648)  : maskpack int32->bitmask + per-row window bits (wrow)
// ---------------------------------------------------------------------------
__global__ __launch_bounds__(256) void prep_kernel(
    const float* __restrict__ Wq, const float* __restrict__ Wk,
    const float* __restrict__ Wv, const float* __restrict__ Wo,
    u16* __restrict__ Wt,
    const float* __restrict__ hid, const float* __restrict__ cross,
    const float* __restrict__ g, const float* __restrict__ bb,
    u16* __restrict__ xln, u16* __restrict__ crossb,
    const int* __restrict__ mask, u32* __restrict__ bits,
    u32* __restrict__ wrow)
{
    int id = blockIdx.x;
    int t = threadIdx.x;

    if (id < 576) {
        int mat = id / 144, rem = id % 144;
        int by = rem / 12, bx = rem % 12;
        const float* src = (mat == 0) ? Wq : (mat == 1) ? Wk : (mat == 2) ? Wv : Wo;
        u16* dst = Wt + (size_t)mat * 768 * 768;

        __shared__ float sm[64][68];  // +4 pad
        int r0 = by * 64, c0 = bx * 64;
        #pragma unroll
        for (int it = 0; it < 4; ++it) {
            int c = t + it * 256;
            int r = c >> 4, sg = c & 15;
            *(float4*)&sm[r][sg * 4] = *(const float4*)&src[(size_t)(r0 + r) * 768 + c0 + sg * 4];
        }
        __syncthreads();
        #pragma unroll
        for (int it = 0; it < 2; ++it) {
            int c = t + it * 256;
            int rr = c >> 3, sg = c & 7;
            u16 tmp[8] __attribute__((aligned(16)));
            #pragma unroll
            for (int j = 0; j < 8; ++j) tmp[j] = f2b(sm[sg * 8 + j][rr]);
            *(u32x4*)&dst[(size_t)(c0 + rr) * 768 + r0 + sg * 8] = *(u32x4*)tmp;
        }
        return;
    }

    if (id < 2624) {
        int lid = id - 576;
        int y = lid >> 10, bx = lid & 1023;
        int wv = t >> 6, lane = t & 63;
        int row = bx * 4 + wv;

        if (y == 1) {
            const float* xr = cross + (size_t)row * 768;
            u16* o = crossb + (size_t)row * 768;
            #pragma unroll
            for (int c = 0; c < 3; ++c) {
                float4 f = *(const float4*)&xr[c * 256 + lane * 4];
                u16 t4[4] __attribute__((aligned(8)));
                t4[0] = f2b(f.x); t4[1] = f2b(f.y); t4[2] = f2b(f.z); t4[3] = f2b(f.w);
                *(u32x2*)&o[c * 256 + lane * 4] = *(u32x2*)t4;
            }
            return;
        }

        const float* xr = hid + (size_t)row * 768;
        float v[12];
        float s = 0.f, s2 = 0.f;
        #pragma unroll
        for (int c = 0; c < 3; ++c) {
            float4 f = *(const float4*)&xr[c * 256 + lane * 4];
            v[c*4+0] = f.x; v[c*4+1] = f.y; v[c*4+2] = f.z; v[c*4+3] = f.w;
            s  += f.x + f.y + f.z + f.w;
            s2 += f.x*f.x + f.y*f.y + f.z*f.z + f.w*f.w;
        }
        #pragma unroll
        for (int off = 1; off < 64; off <<= 1) {
            s  += __shfl_xor(s,  off, 64);
            s2 += __shfl_xor(s2, off, 64);
        }
        float mu  = s  * (1.f / 768.f);
        float var = s2 * (1.f / 768.f) - mu * mu;
        float rs  = 1.f / sqrtf(var + 1e-5f);
        #pragma unroll
        for (int c = 0; c < 3; ++c) {
            float4 gg = *(const float4*)&g [c * 256 + lane * 4];
            float4 bv = *(const float4*)&bb[c * 256 + lane * 4];
            u16 o[4] __attribute__((aligned(8)));
            o[0] = f2b((v[c*4+0] - mu) * rs * gg.x + bv.x);
            o[1] = f2b((v[c*4+1] - mu) * rs * gg.y + bv.y);
            o[2] = f2b((v[c*4+2] - mu) * rs * gg.z + bv.z);
            o[3] = f2b((v[c*4+3] - mu) * rs * gg.w + bv.w);
            *(u32x2*)&xln[(size_t)row * 768 + c * 256 + lane * 4] = *(u32x2*)o;
        }
        return;
    }

    {
        int mid = id - 2624;                    // 0..1023
        int w = mid * 256 + t;                  // word index; row = w>>6
        const int4* p = (const int4*)(mask + (size_t)w * 32);
        u32 v = 0;
        #pragma unroll
        for (int i = 0; i < 8; ++i) {
            int4 m = p[i];
            v |= ((m.x != 0) ? 1u : 0u) << (4 * i + 0);
            v |= ((m.y != 0) ? 1u : 0u) << (4 * i + 1);
            v |= ((m.z != 0) ? 1u : 0u) << (4 * i + 2);
            v |= ((m.w != 0) ? 1u : 0u) << (4 * i + 3);
        }
        bits[w] = v;
        unsigned long long ball = __ballot(v == 0xffffffffu);
        if ((t & 63) == 0) {
            u32 wr = 0;
            #pragma unroll
            for (int kt = 0; kt < 32; ++kt)
                if (((ball >> (2 * kt)) & 3ull) == 3ull) wr |= (1u << kt);
            wrow[w >> 6] = wr;
        }
    }
}

// ---------------------------------------------------------------------------
// Shared GEMM mainloop: C[128x128] += A[128xK] * Wt[128xK]^T, BK=64.
// v2: DOUBLE-BUFFERED prefetch (T3-minimum 2-phase). Stage of tile kt+1 is
// issued BEFORE the compute of tile kt; the single __syncthreads() per
// iteration (vmcnt(0)+lgkmcnt(0)+barrier) then drains loads that have had a
// full compute phase to fly — global->LDS latency hides under the 32 MFMAs
// instead of serializing. 1 barrier/iter instead of 2.
// XOR-chunk-swizzled [128][64] LDS tiles as before (conflict-free b128 reads).
// ---------------------------------------------------------------------------
__device__ __forceinline__ void gemm128_main(const u16* __restrict__ A,
                                             const u16* __restrict__ W,
                                             f32x4 acc[4][4])
{
    __shared__ __attribute__((aligned(16))) u16 AsL[2][128 * 64];
    __shared__ __attribute__((aligned(16))) u16 BsL[2][128 * 64];
    int m0 = blockIdx.x * 128, n0 = blockIdx.y * 128;
    int t = threadIdx.x;
    int wv = t >> 6, lane = t & 63, lm = lane & 15, quad = lane >> 4;
    int wr = wv >> 1, wc = wv & 1;

    auto STAGE = [&](int pp, int kt) {
        #pragma unroll
        for (int it = 0; it < 4; ++it) {
            int c = t + it * 256;
            int row = c >> 3, cs = (c & 7) ^ (row & 7);
            async16(A + (size_t)(m0 + row) * 768 + kt * 64 + cs * 8, &AsL[pp][c * 8]);
            async16(W + (size_t)(n0 + row) * 768 + kt * 64 + cs * 8, &BsL[pp][c * 8]);
        }
    };

    STAGE(0, 0);
    __syncthreads();                             // vmcnt(0) drained by barrier

    for (int kt = 0; kt < 768 / 64; ++kt) {
        int p = kt & 1;
        if (kt < 768 / 64 - 1) STAGE(p ^ 1, kt + 1);   // prefetch next tile
        #pragma unroll
        for (int kk = 0; kk < 2; ++kk) {
            bf16x8_t af[4], bfv[4];
            #pragma unroll
            for (int i = 0; i < 4; ++i) {
                int r = wr * 64 + i * 16 + lm;
                af[i] = *(const bf16x8_t*)&AsL[p][(r * 8 + ((kk * 4 + quad) ^ (r & 7))) * 8];
            }
            #pragma unroll
            for (int j = 0; j < 4; ++j) {
                int r = wc * 64 + j * 16 + lm;
                bfv[j] = *(const bf16x8_t*)&BsL[p][(r * 8 + ((kk * 4 + quad) ^ (r & 7))) * 8];
            }
            #pragma unroll
            for (int i = 0; i < 4; ++i)
                #pragma unroll
                for (int j = 0; j < 4; ++j)
                    acc[i][j] = MFMA16(af[i], bfv[j], acc[i][j]);
        }
        __syncthreads();   // prefetch landed + all waves done reading buf[p]
    }
}

// ---------------------------------------------------------------------------
// Kernel 2: fused QKV projection. z: 0=Q, 1=K, 2=V. V is written TRANSPOSED
// per (b,h): VtG[(b*12+h)*64 + d][s], so attn stages it with straight copies.
// ---------------------------------------------------------------------------
__global__ __launch_bounds__(256) void qkv_gemm(
    const u16* __restrict__ xln, const u16* __restrict__ crossb,
    const u16* __restrict__ Wt,  const float* __restrict__ bq,
    const float* __restrict__ bk, const float* __restrict__ bv,
    const float* __restrict__ mem,
    u16* __restrict__ Qb, u16* __restrict__ Kb, u16* __restrict__ VtG)
{
    int z = blockIdx.z;
    const u16* A      = (z == 0) ? xln : crossb;
    const u16* W      = Wt + (size_t)z * 768 * 768;
    const float* bias = (z == 0) ? bq : (z == 1) ? bk : bv;
    const float* mp   = (z == 0) ? (const float*)nullptr : mem + (size_t)(z - 1) * BSS * HH;

    f32x4 z4 = {0.f, 0.f, 0.f, 0.f};
    f32x4 acc[4][4];
    #pragma unroll
    for (int i = 0; i < 4; ++i)
        #pragma unroll
        for (int j = 0; j < 4; ++j) acc[i][j] = z4;

    gemm128_main(A, W, acc);

    int t = threadIdx.x, wv = t >> 6, lane = t & 63, lm = lane & 15, quad = lane >> 4;
    int wr = wv >> 1, wc = wv & 1;
    int row0 = blockIdx.x * 128 + wr * 64 + quad * 4;  // C/D: row = quad*4+reg
    int col0 = blockIdx.y * 128 + wc * 64 + lm;        //      col = lane&15

    if (z == 2) {
        // V: transposed store, 4 row-consecutive elems -> contiguous s -> 8B
        #pragma unroll
        for (int j = 0; j < 4; ++j) {
            int cg = col0 + j * 16;
            float bz = bias[cg];
            int h = cg >> 6, d = cg & 63;
            #pragma unroll
            for (int i = 0; i < 4; ++i) {
                int rg = row0 + i * 16;
                int b = rg >> 11, s = rg & 2047;
                u16 ob[4] __attribute__((aligned(8)));
                #pragma unroll
                for (int e = 0; e < 4; ++e) {
                    float v = acc[i][j][e] + bz + 0.5f * mp[(size_t)(rg + e) * HH + cg];
                    ob[e] = f2b(v);
                }
                *(u32x2*)&VtG[((size_t)(b * NHH + h) * 64 + d) * SS + s] = *(u32x2*)ob;
            }
        }
        return;
    }

    u16* out = (z == 0) ? Qb : Kb;
    #pragma unroll
    for (int j = 0; j < 4; ++j) {
        int cg = col0 + j * 16;
        float bz = bias[cg];
        #pragma unroll
        for (int i = 0; i < 4; ++i) {
            int rg = row0 + i * 16;
            #pragma unroll
            for (int e = 0; e < 4; ++e) {
                float v = acc[i][j][e] + bz;
                if (mp) v += 0.5f * mp[(size_t)(rg + e) * HH + cg];
                out[(size_t)(rg + e) * HH + cg] = f2b(v);
            }
        }
    }
}

// ---------------------------------------------------------------------------
// Kernel 3: flash attention, fixed-max softmax, global split-K.
// v2: DOUBLE-BUFFERED K/V staging — stage tile kt+1 issued before compute of
// tile kt, single __syncthreads() per k-step (was 2). The vmcnt(0) drain at
// the barrier now lands after a full QK+softmax+PV phase, hiding the
// global->LDS latency that previously serialized each k-step.
// LDS 51.2KB -> 3 blocks/CU = grid residency (16x24x2 = 768 blocks, 3/CU),
// so no occupancy loss vs the 34.8KB single-buffer version.
// ---------------------------------------------------------------------------
__global__ __launch_bounds__(512) void attn_kernel(
    const u16* __restrict__ Q, const u16* __restrict__ K,
    const u16* __restrict__ VtG, const u32* __restrict__ mbits,
    const u32* __restrict__ wrow,
    u16* __restrict__ Pacc, float* __restrict__ Pl, int ksteps)
{
    __shared__ __attribute__((aligned(16))) u16   KsL[2][64 * 64];
    __shared__ __attribute__((aligned(16))) u16   VtL[2][64 * 64];
    __shared__ __attribute__((aligned(16))) short Ps[8][16][72];

    int qt = blockIdx.x;             // 0..15 q-tiles (128 rows each)
    int bh = blockIdx.y;             // 0..23
    int z  = blockIdx.z;             // split index
    int b = bh / NHH, h = bh % NHH;
    int t = threadIdx.x;
    int wv = t >> 6, lane = t & 63, lm = lane & 15, quad = lane >> 4;
    int r7 = lm & 7;

    int qrow_g = b * SS + qt * 128 + wv * 16;
    const u16* qp = Q + (size_t)(qrow_g + lm) * HH + h * 64;
    bf16x8_t qf0 = *(const bf16x8_t*)&qp[quad * 8];
    bf16x8_t qf1 = *(const bf16x8_t*)&qp[32 + quad * 8];

    f32x4 z4 = {0.f, 0.f, 0.f, 0.f};
    f32x4 acc_o[4] = {z4, z4, z4, z4};
    float l_part[4] = {0.f, 0.f, 0.f, 0.f};

    const float SC = 0.18033688011112042f;       // log2(e)/sqrt(64)
    int qloc = qt * 128 + wv * 16 + quad * 4;

    u32 wand = wrow[b * SS + qloc + 0] & wrow[b * SS + qloc + 1] &
               wrow[b * SS + qloc + 2] & wrow[b * SS + qloc + 3];

    // staging: 512 threads cover 512 chunks per tile (one async16 each)
    int kr = t >> 3, cs = (t & 7) ^ (kr & 7);
    const u16* Kb0 = K + (size_t)(b * SS) * HH + h * 64;
    const u16* Vb0 = VtG + (size_t)bh * 64 * SS;

    auto STAGE = [&](int pp, int kt) {
        int k0 = kt * 64;
        async16(Kb0 + (size_t)(k0 + kr) * HH + cs * 8, &KsL[pp][t * 8]);
        async16(Vb0 + (size_t)kr * SS + k0 + cs * 8,   &VtL[pp][t * 8]);
    };

    int kt0 = z * ksteps, ktE = kt0 + ksteps;
    STAGE(0, kt0);
    __syncthreads();                 // prologue tile resident

    for (int kt = kt0; kt < ktE; ++kt) {
        int p = (kt - kt0) & 1;
        if (kt + 1 < ktE) STAGE(p ^ 1, kt + 1);   // prefetch next tile

        // scores: 16(q) x 64(k) per wave
        f32x4 sc[4];
        #pragma unroll
        for (int k16 = 0; k16 < 4; ++k16) {
            int rowk = k16 * 16 + lm;
            bf16x8_t kf0 = *(const bf16x8_t*)&KsL[p][(rowk * 8 + (quad ^ r7)) * 8];
            bf16x8_t kf1 = *(const bf16x8_t*)&KsL[p][(rowk * 8 + ((quad ^ 4) ^ r7)) * 8];
            f32x4 a = z4;
            a = MFMA16(qf0, kf0, a);
            a = MFMA16(qf1, kf1, a);
            sc[k16] = a;
        }

        // mask slow path only if some window bit is 0
        if (!__all((int)((wand >> kt) & 1u))) {
            #pragma unroll
            for (int e = 0; e < 4; ++e) {
                u32x2 u = *(const u32x2*)&mbits[(size_t)(b * SS + qloc + e) * (SS / 32) + kt * 2];
                unsigned long long mw = ((unsigned long long)u.y << 32) | (unsigned long long)u.x;
                #pragma unroll
                for (int k16 = 0; k16 < 4; ++k16)
                    if (!((mw >> (k16 * 16 + lm)) & 1ull)) sc[k16][e] = -3.0e38f;
            }
        }

        // fixed-max softmax: p = exp2(s*SC); per-lane l partials
        #pragma unroll
        for (int k16 = 0; k16 < 4; ++k16) {
            #pragma unroll
            for (int e = 0; e < 4; ++e) {
                float pv = __builtin_amdgcn_exp2f(sc[k16][e] * SC);
                sc[k16][e] = pv;
                l_part[e] += pv;
            }
        }

        // P (C layout) -> A-operand layout; column-group write swizzle
        #pragma unroll
        for (int k16 = 0; k16 < 4; ++k16) {
            int colg = ((k16 + quad) & 3) * 16;
            #pragma unroll
            for (int e = 0; e < 4; ++e) {
                float pv = sc[k16][e];
                u32 pb = __builtin_bit_cast(u32, pv);
                Ps[wv][quad * 4 + e][colg + lm] = (short)((pb + 0x8000u) >> 16);
            }
        }
        __asm__ volatile("" ::: "memory");

        // PV: acc_o[q][d] += P[q][k] * V[k][d]
        #pragma unroll
        for (int cc = 0; cc < 2; ++cc) {
            int k16r = cc * 2 + (quad >> 1);
            int colg = ((k16r + (lm >> 2)) & 3) * 16 + (quad & 1) * 8;
            bf16x8_t pf = *(const bf16x8_t*)&Ps[wv][lm][colg];
            #pragma unroll
            for (int j = 0; j < 4; ++j) {
                bf16x8_t vf = *(const bf16x8_t*)&VtL[p][((j * 16 + lm) * 8 + ((cc * 4 + quad) ^ r7)) * 8];
                acc_o[j] = MFMA16(pf, vf, acc_o[j]);
            }
        }

        __syncthreads();   // prefetch landed + all waves done reading buf[p]
    }

    // one-time l reduction across the 16 lanes of the row group
    #pragma unroll
    for (int off = 1; off < 16; off <<= 1) {
        #pragma unroll
        for (int e = 0; e < 4; ++e)
            l_part[e] += __shfl_xor(l_part[e], off, 64);
    }

    // epilogue: write unnormalized partials
    size_t prow = ((size_t)z * NBH + bh) * SS + qt * 128 + wv * 16 + quad * 4;
    #pragma unroll
    for (int j = 0; j < 4; ++j)
        #pragma unroll
        for (int e = 0; e < 4; ++e)
            Pacc[(prow + e) * 64 + j * 16 + lm] = f2b(acc_o[j][e]);
    if (lm == 0) {
        #pragma unroll
        for (int e = 0; e < 4; ++e)
            Pl[prow + e] = l_part[e];
    }
}

// ---------------------------------------------------------------------------
// Kernel 3b: merge split-K partials -> AO (bf16 [B*S][H] layout).
// ---------------------------------------------------------------------------
__global__ __launch_bounds__(256) void attn_merge(
    const u16* __restrict__ Pacc, const float* __restrict__ Pl,
    u16* __restrict__ AO)
{
    int t = threadIdx.x;
    int r = blockIdx.x * 64 + (t >> 2);          // bh*2048 + q
    int dseg = (t & 3) * 16;

    float lsum = Pl[r] + Pl[(size_t)ROWS_BH + r];

    float o[16];
    #pragma unroll
    for (int i = 0; i < 16; ++i) o[i] = 0.f;
    #pragma unroll
    for (int s = 0; s < NSPLIT; ++s) {
        const u16* ap = &Pacc[((size_t)s * ROWS_BH + r) * 64 + dseg];
        u32x4 a0 = *(const u32x4*)ap;
        u32x4 a1 = *(const u32x4*)(ap + 8);
        u32 wa[8];
        wa[0]=a0.x; wa[1]=a0.y; wa[2]=a0.z; wa[3]=a0.w;
        wa[4]=a1.x; wa[5]=a1.y; wa[6]=a1.z; wa[7]=a1.w;
        #pragma unroll
        for (int i = 0; i < 8; ++i) {
            o[2*i]   += b2f((u16)(wa[i] & 0xffff));
            o[2*i+1] += b2f((u16)(wa[i] >> 16));
        }
    }
    float inv = 1.f / lsum;
    int bh = r >> 11, q = r & 2047;
    int b = bh / NHH, h = bh % NHH;
    u16 ob[16] __attribute__((aligned(16)));
    #pragma unroll
    for (int i = 0; i < 16; ++i) ob[i] = f2b(o[i] * inv);
    u16* op = &AO[((size_t)(b * SS + q)) * HH + h * 64 + dseg];
    *(u32x4*)op       = *(u32x4*)ob;
    *(u32x4*)(op + 8) = *(u32x4*)(ob + 8);
}

// ---------------------------------------------------------------------------
// Kernel 4: output projection + fp32 epilogue, fp32 output.
// ---------------------------------------------------------------------------
__global__ __launch_bounds__(256) void out_gemm(
    const u16* __restrict__ AO, const u16* __restrict__ Wt,
    const float* __restrict__ bo, const float* __restrict__ gate,
    const float* __restrict__ gbias, const float* __restrict__ dyn,
    float* __restrict__ out)
{
    f32x4 z4 = {0.f, 0.f, 0.f, 0.f};
    f32x4 acc[4][4];
    #pragma unroll
    for (int i = 0; i < 4; ++i)
        #pragma unroll
        for (int j = 0; j < 4; ++j) acc[i][j] = z4;

    gemm128_main(AO, Wt, acc);

    float gv = gate[0];
    float gb = gbias[0];
    int t = threadIdx.x, wv = t >> 6, lane = t & 63, lm = lane & 15, quad = lane >> 4;
    int wr = wv >> 1, wc = wv & 1;
    int row0 = blockIdx.x * 128 + wr * 64 + quad * 4;
    int col0 = blockIdx.y * 128 + wc * 64 + lm;
    #pragma unroll
    for (int j = 0; j < 4; ++j) {
        int cg = col0 + j * 16;
        float bz = bo[cg];
        #pragma unroll
        for (int i = 0; i < 4; ++i) {
            int rg = row0 + i * 16;
            #pragma unroll
            for (int e = 0; e < 4; ++e) {
                float v = acc[i][j][e] + bz;
                v = v * gv + gb;
                v *= dyn[rg + e];
                out[(size_t)(rg + e) * HH + cg] = v;
            }
        }
    }
}

// ---------------------------------------------------------------------------
extern "C" void kernel_launch(void* const* d_in, const int* in_sizes, int n_in,
                              void* d_out, int out_size, void* d_ws, size_t ws_size,
                              hipStream_t stream)
{
    (void)in_sizes; (void)n_in; (void)out_size; (void)ws_size;

    const float* hid   = (const float*)d_in[0];
    const float* cross = (const float*)d_in[1];
    const int*   amask = (const int*)d_in[2];
    const float* mem   = (const float*)d_in[3];
    const float* dyn   = (const float*)d_in[4];
    const float* Wq    = (const float*)d_in[5];
    const float* bq    = (const float*)d_in[6];
    const float* Wk    = (const float*)d_in[7];
    const float* bk    = (const float*)d_in[8];
    const float* Wv    = (const float*)d_in[9];
    const float* bv    = (const float*)d_in[10];
    const float* Wo    = (const float*)d_in[11];
    const float* bo    = (const float*)d_in[12];
    const float* gate  = (const float*)d_in[13];
    const float* gbias = (const float*)d_in[14];
    const float* lng   = (const float*)d_in[15];
    const float* lnb   = (const float*)d_in[16];

    // workspace layout (37.3 MB, proven footprint):
    //   Pacc (12.58 MB) overlays xln+crb (dead after qkv_gemm)
    //   Pl (393 KB) overlays Wt[0]=Wq^T (dead after qkv_gemm)
    //   AO overlays Kb (dead after attn)
    char* p = (char*)d_ws;
    u16* Wt   = (u16*)p; p += (size_t)4 * 768 * 768 * 2;        // 4.72 MB
    u32* mb   = (u32*)p; p += (size_t)BB * SS * (SS / 32) * 4;  // 1.05 MB
    u32* wrow = (u32*)p; p += (size_t)BSS * 4;                  // 16 KB
    u16* xln  = (u16*)p; p += (size_t)BSS * HH * 2;             // 6.29 MB
    u16* crb  = (u16*)p; p += (size_t)BSS * HH * 2;             // 6.29 MB
    u16* Qb   = (u16*)p; p += (size_t)BSS * HH * 2;
    u16* Kb   = (u16*)p; p += (size_t)BSS * HH * 2;
    u16* VtG  = (u16*)p; p += (size_t)BSS * HH * 2;             // V transposed [bh][d][s]
    u16* Pacc  = xln;            // 2 x 24 x 2048 x 64 bf16 = 12.58 MB
    float* Pl  = (float*)Wt;     // 2 x 49152 fp32 = 393 KB (< Wq^T's 1.18 MB)
    u16* AO    = Kb;

    prep_kernel <<<dim3(3648),           256, 0, stream>>>(
        Wq, Wk, Wv, Wo, Wt, hid, cross, lng, lnb, xln, crb, amask, mb, wrow);
    qkv_gemm    <<<dim3(32, 6, 3),       256, 0, stream>>>(
        xln, crb, Wt, bq, bk, bv, mem, Qb, Kb, VtG);
    attn_kernel <<<dim3(16, 24, NSPLIT), 512, 0, stream>>>(
        Qb, Kb, VtG, mb, wrow, Pacc, Pl, SS / 64 / NSPLIT);
    attn_merge  <<<dim3(ROWS_BH / 64),   256, 0, stream>>>(Pacc, Pl, AO);
    out_gemm    <<<dim3(32, 6),          256, 0, stream>>>(
        AO, Wt + (size_t)3 * 768 * 768, bo, gate, gbias, dyn, (float*)d_out);
}

// Round 2
// 246.278 us; speedup vs baseline: 1.0651x; 1.0606x over previous
//
#include <hip/hip_runtime.h>
#include <hip/hip_bf16.h>
#include <stdint.h>

// Problem constants
#define BB   2
#define SS   2048
#define HH   768
#define NHH  12
#define HDD  64
#define BSS  (BB*SS)          // 4096 rows
#define NBH  (BB*NHH)         // 24
#define ROWS_BH (NBH*SS)      // 49152
#define NSPLIT 2

typedef unsigned short u16;
typedef unsigned int   u32;
typedef __attribute__((ext_vector_type(8))) short bf16x8_t;   // 8 bf16 (4 VGPRs) - MFMA A/B frag
typedef __attribute__((ext_vector_type(4))) float f32x4;      // MFMA C/D frag
typedef __attribute__((ext_vector_type(2))) u32   u32x2;
typedef __attribute__((ext_vector_type(4))) u32   u32x4;

#define MFMA16(a, b, c) __builtin_amdgcn_mfma_f32_16x16x32_bf16((a), (b), (c), 0, 0, 0)

__device__ __forceinline__ float b2f(u16 u) {
    u32 x = ((u32)u) << 16; float f; __builtin_memcpy(&f, &x, 4); return f;
}
__device__ __forceinline__ u16 f2b(float f) {   // round-to-nearest-even bf16
    u32 x; __builtin_memcpy(&x, &f, 4);
    u32 r = x + 0x7fffu + ((x >> 16) & 1u);
    return (u16)(r >> 16);
}
// async global->LDS 16B DMA (m97 pattern; LDS dest = wave base + lane*16)
__device__ __forceinline__ void async16(const u16* g, u16* l) {
    __builtin_amdgcn_global_load_lds(
        (const __attribute__((address_space(1))) void*)g,
        (__attribute__((address_space(3))) void*)l, 16, 0, 0);
}

// ---------------------------------------------------------------------------
// Kernel 1 (fused prep): blockIdx.x ranges select role.
//   [0,576)      : transpose fp32 768x768 weights -> bf16 Wt[n][k]
//   [576,2624)   : LayerNorm(hidden)->xln (y=0) / cross fp32->bf16 (y=1)
//   [2624,3648)  : maskpack int32->bitmask + per-row window bits (wrow)
// ---------------------------------------------------------------------------
__global__ __launch_bounds__(256) void prep_kernel(
    const float* __restrict__ Wq, const float* __restrict__ Wk,
    const float* __restrict__ Wv, const float* __restrict__ Wo,
    u16* __restrict__ Wt,
    const float* __restrict__ hid, const float* __restrict__ cross,
    const float* __restrict__ g, const float* __restrict__ bb,
    u16* __restrict__ xln, u16* __restrict__ crossb,
    const int* __restrict__ mask, u32* __restrict__ bits,
    u32* __restrict__ wrow)
{
    int id = blockIdx.x;
    int t = threadIdx.x;

    if (id < 576) {
        int mat = id / 144, rem = id % 144;
        int by = rem / 12, bx = rem % 12;
        const float* src = (mat == 0) ? Wq : (mat == 1) ? Wk : (mat == 2) ? Wv : Wo;
        u16* dst = Wt + (size_t)mat * 768 * 768;

        __shared__ float sm[64][68];  // +4 pad
        int r0 = by * 64, c0 = bx * 64;
        #pragma unroll
        for (int it = 0; it < 4; ++it) {
            int c = t + it * 256;
            int r = c >> 4, sg = c & 15;
            *(float4*)&sm[r][sg * 4] = *(const float4*)&src[(size_t)(r0 + r) * 768 + c0 + sg * 4];
        }
        __syncthreads();
        #pragma unroll
        for (int it = 0; it < 2; ++it) {
            int c = t + it * 256;
            int rr = c >> 3, sg = c & 7;
            u16 tmp[8] __attribute__((aligned(16)));
            #pragma unroll
            for (int j = 0; j < 8; ++j) tmp[j] = f2b(sm[sg * 8 + j][rr]);
            *(u32x4*)&dst[(size_t)(c0 + rr) * 768 + r0 + sg * 8] = *(u32x4*)tmp;
        }
        return;
    }

    if (id < 2624) {
        int lid = id - 576;
        int y = lid >> 10, bx = lid & 1023;
        int wv = t >> 6, lane = t & 63;
        int row = bx * 4 + wv;

        if (y == 1) {
            const float* xr = cross + (size_t)row * 768;
            u16* o = crossb + (size_t)row * 768;
            #pragma unroll
            for (int c = 0; c < 3; ++c) {
                float4 f = *(const float4*)&xr[c * 256 + lane * 4];
                u16 t4[4] __attribute__((aligned(8)));
                t4[0] = f2b(f.x); t4[1] = f2b(f.y); t4[2] = f2b(f.z); t4[3] = f2b(f.w);
                *(u32x2*)&o[c * 256 + lane * 4] = *(u32x2*)t4;
            }
            return;
        }

        const float* xr = hid + (size_t)row * 768;
        float v[12];
        float s = 0.f, s2 = 0.f;
        #pragma unroll
        for (int c = 0; c < 3; ++c) {
            float4 f = *(const float4*)&xr[c * 256 + lane * 4];
            v[c*4+0] = f.x; v[c*4+1] = f.y; v[c*4+2] = f.z; v[c*4+3] = f.w;
            s  += f.x + f.y + f.z + f.w;
            s2 += f.x*f.x + f.y*f.y + f.z*f.z + f.w*f.w;
        }
        #pragma unroll
        for (int off = 1; off < 64; off <<= 1) {
            s  += __shfl_xor(s,  off, 64);
            s2 += __shfl_xor(s2, off, 64);
        }
        float mu  = s  * (1.f / 768.f);
        float var = s2 * (1.f / 768.f) - mu * mu;
        float rs  = 1.f / sqrtf(var + 1e-5f);
        #pragma unroll
        for (int c = 0; c < 3; ++c) {
            float4 gg = *(const float4*)&g [c * 256 + lane * 4];
            float4 bv = *(const float4*)&bb[c * 256 + lane * 4];
            u16 o[4] __attribute__((aligned(8)));
            o[0] = f2b((v[c*4+0] - mu) * rs * gg.x + bv.x);
            o[1] = f2b((v[c*4+1] - mu) * rs * gg.y + bv.y);
            o[2] = f2b((v[c*4+2] - mu) * rs * gg.z + bv.z);
            o[3] = f2b((v[c*4+3] - mu) * rs * gg.w + bv.w);
            *(u32x2*)&xln[(size_t)row * 768 + c * 256 + lane * 4] = *(u32x2*)o;
        }
        return;
    }

    {
        int mid = id - 2624;                    // 0..1023
        int w = mid * 256 + t;                  // word index; row = w>>6
        const int4* p = (const int4*)(mask + (size_t)w * 32);
        u32 v = 0;
        #pragma unroll
        for (int i = 0; i < 8; ++i) {
            int4 m = p[i];
            v |= ((m.x != 0) ? 1u : 0u) << (4 * i + 0);
            v |= ((m.y != 0) ? 1u : 0u) << (4 * i + 1);
            v |= ((m.z != 0) ? 1u : 0u) << (4 * i + 2);
            v |= ((m.w != 0) ? 1u : 0u) << (4 * i + 3);
        }
        bits[w] = v;
        unsigned long long ball = __ballot(v == 0xffffffffu);
        if ((t & 63) == 0) {
            u32 wr = 0;
            #pragma unroll
            for (int kt = 0; kt < 32; ++kt)
                if (((ball >> (2 * kt)) & 3ull) == 3ull) wr |= (1u << kt);
            wrow[w >> 6] = wr;
        }
    }
}

// ---------------------------------------------------------------------------
// Shared GEMM mainloop v3: C[64x128] += A[64xK] * Wt[128xK]^T, BK=64.
// TILE SHRUNK 128x128 -> 64x128 for occupancy: grid goes 2.25 -> 4.5
// blocks/CU (all resident, 18 waves/CU) -- the round-1 counters showed the
// GEMMs latency-bound (MfmaUtil 8%, VALU 5%, HBM 13%, Occ 15%), so TLP, not
// intra-block pipelining, is the lever. Single-buffered (24KB LDS, cap 6
// blocks/CU); barrier drains hide under other resident blocks (m97 pattern).
// 4 waves, each computes 32x64 (acc[2][4]); 16 MFMA : 12 ds_read_b128 per
// K-step. XOR-chunk-swizzled LDS tiles (conflict-free b128 reads) unchanged.
// ---------------------------------------------------------------------------
__device__ __forceinline__ void gemm64_main(const u16* __restrict__ A,
                                            const u16* __restrict__ W,
                                            f32x4 acc[2][4])
{
    __shared__ __attribute__((aligned(16))) u16 AsL[64 * 64];
    __shared__ __attribute__((aligned(16))) u16 BsL[128 * 64];
    int m0 = blockIdx.x * 64, n0 = blockIdx.y * 128;
    int t = threadIdx.x;
    int wv = t >> 6, lane = t & 63, lm = lane & 15, quad = lane >> 4;
    int wr = wv >> 1, wc = wv & 1;

    for (int kt = 0; kt < 768 / 64; ++kt) {
        __syncthreads();                         // prev-iter reads done
        #pragma unroll
        for (int it = 0; it < 2; ++it) {         // A: 512 chunks, 2/thread
            int c = t + it * 256;
            int row = c >> 3, cs = (c & 7) ^ (row & 7);
            async16(A + (size_t)(m0 + row) * 768 + kt * 64 + cs * 8, &AsL[c * 8]);
        }
        #pragma unroll
        for (int it = 0; it < 4; ++it) {         // B: 1024 chunks, 4/thread
            int c = t + it * 256;
            int row = c >> 3, cs = (c & 7) ^ (row & 7);
            async16(W + (size_t)(n0 + row) * 768 + kt * 64 + cs * 8, &BsL[c * 8]);
        }
        __syncthreads();                         // vmcnt(0) drained by barrier
        #pragma unroll
        for (int kk = 0; kk < 2; ++kk) {
            bf16x8_t af[2], bfv[4];
            #pragma unroll
            for (int i = 0; i < 2; ++i) {
                int r = wr * 32 + i * 16 + lm;
                af[i] = *(const bf16x8_t*)&AsL[(r * 8 + ((kk * 4 + quad) ^ (r & 7))) * 8];
            }
            #pragma unroll
            for (int j = 0; j < 4; ++j) {
                int r = wc * 64 + j * 16 + lm;
                bfv[j] = *(const bf16x8_t*)&BsL[(r * 8 + ((kk * 4 + quad) ^ (r & 7))) * 8];
            }
            #pragma unroll
            for (int i = 0; i < 2; ++i)
                #pragma unroll
                for (int j = 0; j < 4; ++j)
                    acc[i][j] = MFMA16(af[i], bfv[j], acc[i][j]);
        }
    }
}

// ---------------------------------------------------------------------------
// Kernel 2: fused QKV projection. z: 0=Q, 1=K, 2=V. V is written TRANSPOSED
// per (b,h): VtG[(b*12+h)*64 + d][s], so attn stages it with straight copies.
// Grid now (64, 6, 3) = 1152 blocks.
// ---------------------------------------------------------------------------
__global__ __launch_bounds__(256) void qkv_gemm(
    const u16* __restrict__ xln, const u16* __restrict__ crossb,
    const u16* __restrict__ Wt,  const float* __restrict__ bq,
    const float* __restrict__ bk, const float* __restrict__ bv,
    const float* __restrict__ mem,
    u16* __restrict__ Qb, u16* __restrict__ Kb, u16* __restrict__ VtG)
{
    int z = blockIdx.z;
    const u16* A      = (z == 0) ? xln : crossb;
    const u16* W      = Wt + (size_t)z * 768 * 768;
    const float* bias = (z == 0) ? bq : (z == 1) ? bk : bv;
    const float* mp   = (z == 0) ? (const float*)nullptr : mem + (size_t)(z - 1) * BSS * HH;

    f32x4 z4 = {0.f, 0.f, 0.f, 0.f};
    f32x4 acc[2][4];
    #pragma unroll
    for (int i = 0; i < 2; ++i)
        #pragma unroll
        for (int j = 0; j < 4; ++j) acc[i][j] = z4;

    gemm64_main(A, W, acc);

    int t = threadIdx.x, wv = t >> 6, lane = t & 63, lm = lane & 15, quad = lane >> 4;
    int wr = wv >> 1, wc = wv & 1;
    int row0 = blockIdx.x * 64 + wr * 32 + quad * 4;   // C/D: row = quad*4+reg
    int col0 = blockIdx.y * 128 + wc * 64 + lm;        //      col = lane&15

    if (z == 2) {
        // V: transposed store, 4 row-consecutive elems -> contiguous s -> 8B
        #pragma unroll
        for (int j = 0; j < 4; ++j) {
            int cg = col0 + j * 16;
            float bz = bias[cg];
            int h = cg >> 6, d = cg & 63;
            #pragma unroll
            for (int i = 0; i < 2; ++i) {
                int rg = row0 + i * 16;
                int b = rg >> 11, s = rg & 2047;
                u16 ob[4] __attribute__((aligned(8)));
                #pragma unroll
                for (int e = 0; e < 4; ++e) {
                    float v = acc[i][j][e] + bz + 0.5f * mp[(size_t)(rg + e) * HH + cg];
                    ob[e] = f2b(v);
                }
                *(u32x2*)&VtG[((size_t)(b * NHH + h) * 64 + d) * SS + s] = *(u32x2*)ob;
            }
        }
        return;
    }

    u16* out = (z == 0) ? Qb : Kb;
    #pragma unroll
    for (int j = 0; j < 4; ++j) {
        int cg = col0 + j * 16;
        float bz = bias[cg];
        #pragma unroll
        for (int i = 0; i < 2; ++i) {
            int rg = row0 + i * 16;
            #pragma unroll
            for (int e = 0; e < 4; ++e) {
                float v = acc[i][j][e] + bz;
                if (mp) v += 0.5f * mp[(size_t)(rg + e) * HH + cg];
                out[(size_t)(rg + e) * HH + cg] = f2b(v);
            }
        }
    }
}

// ---------------------------------------------------------------------------
// Kernel 3: flash attention, fixed-max softmax, global split-K.
// DOUBLE-BUFFERED K/V staging (kept from round 1) — stage tile kt+1 issued
// before compute of tile kt, single __syncthreads() per k-step.
// ---------------------------------------------------------------------------
__global__ __launch_bounds__(512) void attn_kernel(
    const u16* __restrict__ Q, const u16* __restrict__ K,
    const u16* __restrict__ VtG, const u32* __restrict__ mbits,
    const u32* __restrict__ wrow,
    u16* __restrict__ Pacc, float* __restrict__ Pl, int ksteps)
{
    __shared__ __attribute__((aligned(16))) u16   KsL[2][64 * 64];
    __shared__ __attribute__((aligned(16))) u16   VtL[2][64 * 64];
    __shared__ __attribute__((aligned(16))) short Ps[8][16][72];

    int qt = blockIdx.x;             // 0..15 q-tiles (128 rows each)
    int bh = blockIdx.y;             // 0..23
    int z  = blockIdx.z;             // split index
    int b = bh / NHH, h = bh % NHH;
    int t = threadIdx.x;
    int wv = t >> 6, lane = t & 63, lm = lane & 15, quad = lane >> 4;
    int r7 = lm & 7;

    int qrow_g = b * SS + qt * 128 + wv * 16;
    const u16* qp = Q + (size_t)(qrow_g + lm) * HH + h * 64;
    bf16x8_t qf0 = *(const bf16x8_t*)&qp[quad * 8];
    bf16x8_t qf1 = *(const bf16x8_t*)&qp[32 + quad * 8];

    f32x4 z4 = {0.f, 0.f, 0.f, 0.f};
    f32x4 acc_o[4] = {z4, z4, z4, z4};
    float l_part[4] = {0.f, 0.f, 0.f, 0.f};

    const float SC = 0.18033688011112042f;       // log2(e)/sqrt(64)
    int qloc = qt * 128 + wv * 16 + quad * 4;

    u32 wand = wrow[b * SS + qloc + 0] & wrow[b * SS + qloc + 1] &
               wrow[b * SS + qloc + 2] & wrow[b * SS + qloc + 3];

    // staging: 512 threads cover 512 chunks per tile (one async16 each)
    int kr = t >> 3, cs = (t & 7) ^ (kr & 7);
    const u16* Kb0 = K + (size_t)(b * SS) * HH + h * 64;
    const u16* Vb0 = VtG + (size_t)bh * 64 * SS;

    auto STAGE = [&](int pp, int kt) {
        int k0 = kt * 64;
        async16(Kb0 + (size_t)(k0 + kr) * HH + cs * 8, &KsL[pp][t * 8]);
        async16(Vb0 + (size_t)kr * SS + k0 + cs * 8,   &VtL[pp][t * 8]);
    };

    int kt0 = z * ksteps, ktE = kt0 + ksteps;
    STAGE(0, kt0);
    __syncthreads();                 // prologue tile resident

    for (int kt = kt0; kt < ktE; ++kt) {
        int p = (kt - kt0) & 1;
        if (kt + 1 < ktE) STAGE(p ^ 1, kt + 1);   // prefetch next tile

        // scores: 16(q) x 64(k) per wave
        f32x4 sc[4];
        #pragma unroll
        for (int k16 = 0; k16 < 4; ++k16) {
            int rowk = k16 * 16 + lm;
            bf16x8_t kf0 = *(const bf16x8_t*)&KsL[p][(rowk * 8 + (quad ^ r7)) * 8];
            bf16x8_t kf1 = *(const bf16x8_t*)&KsL[p][(rowk * 8 + ((quad ^ 4) ^ r7)) * 8];
            f32x4 a = z4;
            a = MFMA16(qf0, kf0, a);
            a = MFMA16(qf1, kf1, a);
            sc[k16] = a;
        }

        // mask slow path only if some window bit is 0
        if (!__all((int)((wand >> kt) & 1u))) {
            #pragma unroll
            for (int e = 0; e < 4; ++e) {
                u32x2 u = *(const u32x2*)&mbits[(size_t)(b * SS + qloc + e) * (SS / 32) + kt * 2];
                unsigned long long mw = ((unsigned long long)u.y << 32) | (unsigned long long)u.x;
                #pragma unroll
                for (int k16 = 0; k16 < 4; ++k16)
                    if (!((mw >> (k16 * 16 + lm)) & 1ull)) sc[k16][e] = -3.0e38f;
            }
        }

        // fixed-max softmax: p = exp2(s*SC); per-lane l partials
        #pragma unroll
        for (int k16 = 0; k16 < 4; ++k16) {
            #pragma unroll
            for (int e = 0; e < 4; ++e) {
                float pv = __builtin_amdgcn_exp2f(sc[k16][e] * SC);
                sc[k16][e] = pv;
                l_part[e] += pv;
            }
        }

        // P (C layout) -> A-operand layout; column-group write swizzle
        #pragma unroll
        for (int k16 = 0; k16 < 4; ++k16) {
            int colg = ((k16 + quad) & 3) * 16;
            #pragma unroll
            for (int e = 0; e < 4; ++e) {
                float pv = sc[k16][e];
                u32 pb = __builtin_bit_cast(u32, pv);
                Ps[wv][quad * 4 + e][colg + lm] = (short)((pb + 0x8000u) >> 16);
            }
        }
        __asm__ volatile("" ::: "memory");

        // PV: acc_o[q][d] += P[q][k] * V[k][d]
        #pragma unroll
        for (int cc = 0; cc < 2; ++cc) {
            int k16r = cc * 2 + (quad >> 1);
            int colg = ((k16r + (lm >> 2)) & 3) * 16 + (quad & 1) * 8;
            bf16x8_t pf = *(const bf16x8_t*)&Ps[wv][lm][colg];
            #pragma unroll
            for (int j = 0; j < 4; ++j) {
                bf16x8_t vf = *(const bf16x8_t*)&VtL[p][((j * 16 + lm) * 8 + ((cc * 4 + quad) ^ r7)) * 8];
                acc_o[j] = MFMA16(pf, vf, acc_o[j]);
            }
        }

        __syncthreads();   // prefetch landed + all waves done reading buf[p]
    }

    // one-time l reduction across the 16 lanes of the row group
    #pragma unroll
    for (int off = 1; off < 16; off <<= 1) {
        #pragma unroll
        for (int e = 0; e < 4; ++e)
            l_part[e] += __shfl_xor(l_part[e], off, 64);
    }

    // epilogue: write unnormalized partials
    size_t prow = ((size_t)z * NBH + bh) * SS + qt * 128 + wv * 16 + quad * 4;
    #pragma unroll
    for (int j = 0; j < 4; ++j)
        #pragma unroll
        for (int e = 0; e < 4; ++e)
            Pacc[(prow + e) * 64 + j * 16 + lm] = f2b(acc_o[j][e]);
    if (lm == 0) {
        #pragma unroll
        for (int e = 0; e < 4; ++e)
            Pl[prow + e] = l_part[e];
    }
}

// ---------------------------------------------------------------------------
// Kernel 3b: merge split-K partials -> AO (bf16 [B*S][H] layout).
// ---------------------------------------------------------------------------
__global__ __launch_bounds__(256) void attn_merge(
    const u16* __restrict__ Pacc, const float* __restrict__ Pl,
    u16* __restrict__ AO)
{
    int t = threadIdx.x;
    int r = blockIdx.x * 64 + (t >> 2);          // bh*2048 + q
    int dseg = (t & 3) * 16;

    float lsum = Pl[r] + Pl[(size_t)ROWS_BH + r];

    float o[16];
    #pragma unroll
    for (int i = 0; i < 16; ++i) o[i] = 0.f;
    #pragma unroll
    for (int s = 0; s < NSPLIT; ++s) {
        const u16* ap = &Pacc[((size_t)s * ROWS_BH + r) * 64 + dseg];
        u32x4 a0 = *(const u32x4*)ap;
        u32x4 a1 = *(const u32x4*)(ap + 8);
        u32 wa[8];
        wa[0]=a0.x; wa[1]=a0.y; wa[2]=a0.z; wa[3]=a0.w;
        wa[4]=a1.x; wa[5]=a1.y; wa[6]=a1.z; wa[7]=a1.w;
        #pragma unroll
        for (int i = 0; i < 8; ++i) {
            o[2*i]   += b2f((u16)(wa[i] & 0xffff));
            o[2*i+1] += b2f((u16)(wa[i] >> 16));
        }
    }
    float inv = 1.f / lsum;
    int bh = r >> 11, q = r & 2047;
    int b = bh / NHH, h = bh % NHH;
    u16 ob[16] __attribute__((aligned(16)));
    #pragma unroll
    for (int i = 0; i < 16; ++i) ob[i] = f2b(o[i] * inv);
    u16* op = &AO[((size_t)(b * SS + q)) * HH + h * 64 + dseg];
    *(u32x4*)op       = *(u32x4*)ob;
    *(u32x4*)(op + 8) = *(u32x4*)(ob + 8);
}

// ---------------------------------------------------------------------------
// Kernel 4: output projection + fp32 epilogue, fp32 output.
// Grid now (64, 6) = 384 blocks.
// ---------------------------------------------------------------------------
__global__ __launch_bounds__(256) void out_gemm(
    const u16* __restrict__ AO, const u16* __restrict__ Wt,
    const float* __restrict__ bo, const float* __restrict__ gate,
    const float* __restrict__ gbias, const float* __restrict__ dyn,
    float* __restrict__ out)
{
    f32x4 z4 = {0.f, 0.f, 0.f, 0.f};
    f32x4 acc[2][4];
    #pragma unroll
    for (int i = 0; i < 2; ++i)
        #pragma unroll
        for (int j = 0; j < 4; ++j) acc[i][j] = z4;

    gemm64_main(AO, Wt, acc);

    float gv = gate[0];
    float gb = gbias[0];
    int t = threadIdx.x, wv = t >> 6, lane = t & 63, lm = lane & 15, quad = lane >> 4;
    int wr = wv >> 1, wc = wv & 1;
    int row0 = blockIdx.x * 64 + wr * 32 + quad * 4;
    int col0 = blockIdx.y * 128 + wc * 64 + lm;
    #pragma unroll
    for (int j = 0; j < 4; ++j) {
        int cg = col0 + j * 16;
        float bz = bo[cg];
        #pragma unroll
        for (int i = 0; i < 2; ++i) {
            int rg = row0 + i * 16;
            #pragma unroll
            for (int e = 0; e < 4; ++e) {
                float v = acc[i][j][e] + bz;
                v = v * gv + gb;
                v *= dyn[rg + e];
                out[(size_t)(rg + e) * HH + cg] = v;
            }
        }
    }
}

// ---------------------------------------------------------------------------
extern "C" void kernel_launch(void* const* d_in, const int* in_sizes, int n_in,
                              void* d_out, int out_size, void* d_ws, size_t ws_size,
                              hipStream_t stream)
{
    (void)in_sizes; (void)n_in; (void)out_size; (void)ws_size;

    const float* hid   = (const float*)d_in[0];
    const float* cross = (const float*)d_in[1];
    const int*   amask = (const int*)d_in[2];
    const float* mem   = (const float*)d_in[3];
    const float* dyn   = (const float*)d_in[4];
    const float* Wq    = (const float*)d_in[5];
    const float* bq    = (const float*)d_in[6];
    const float* Wk    = (const float*)d_in[7];
    const float* bk    = (const float*)d_in[8];
    const float* Wv    = (const float*)d_in[9];
    const float* bv    = (const float*)d_in[10];
    const float* Wo    = (const float*)d_in[11];
    const float* bo    = (const float*)d_in[12];
    const float* gate  = (const float*)d_in[13];
    const float* gbias = (const float*)d_in[14];
    const float* lng   = (const float*)d_in[15];
    const float* lnb   = (const float*)d_in[16];

    // workspace layout (37.3 MB, proven footprint):
    //   Pacc (12.58 MB) overlays xln+crb (dead after qkv_gemm)
    //   Pl (393 KB) overlays Wt[0]=Wq^T (dead after qkv_gemm)
    //   AO overlays Kb (dead after attn)
    char* p = (char*)d_ws;
    u16* Wt   = (u16*)p; p += (size_t)4 * 768 * 768 * 2;        // 4.72 MB
    u32* mb   = (u32*)p; p += (size_t)BB * SS * (SS / 32) * 4;  // 1.05 MB
    u32* wrow = (u32*)p; p += (size_t)BSS * 4;                  // 16 KB
    u16* xln  = (u16*)p; p += (size_t)BSS * HH * 2;             // 6.29 MB
    u16* crb  = (u16*)p; p += (size_t)BSS * HH * 2;             // 6.29 MB
    u16* Qb   = (u16*)p; p += (size_t)BSS * HH * 2;
    u16* Kb   = (u16*)p; p += (size_t)BSS * HH * 2;
    u16* VtG  = (u16*)p; p += (size_t)BSS * HH * 2;             // V transposed [bh][d][s]
    u16* Pacc  = xln;            // 2 x 24 x 2048 x 64 bf16 = 12.58 MB
    float* Pl  = (float*)Wt;     // 2 x 49152 fp32 = 393 KB (< Wq^T's 1.18 MB)
    u16* AO    = Kb;

    prep_kernel <<<dim3(3648),           256, 0, stream>>>(
        Wq, Wk, Wv, Wo, Wt, hid, cross, lng, lnb, xln, crb, amask, mb, wrow);
    qkv_gemm    <<<dim3(64, 6, 3),       256, 0, stream>>>(
        xln, crb, Wt, bq, bk, bv, mem, Qb, Kb, VtG);
    attn_kernel <<<dim3(16, 24, NSPLIT), 512, 0, stream>>>(
        Qb, Kb, VtG, mb, wrow, Pacc, Pl, SS / 64 / NSPLIT);
    attn_merge  <<<dim3(ROWS_BH / 64),   256, 0, stream>>>(Pacc, Pl, AO);
    out_gemm    <<<dim3(64, 6),          256, 0, stream>>>(
        AO, Wt + (size_t)3 * 768 * 768, bo, gate, gbias, dyn, (float*)d_out);
}

// Round 3
// 240.549 us; speedup vs baseline: 1.0904x; 1.0238x over previous
//
#include <hip/hip_runtime.h>
#include <hip/hip_bf16.h>
#include <stdint.h>

// Problem constants
#define BB   2
#define SS   2048
#define HH   768
#define NHH  12
#define HDD  64
#define BSS  (BB*SS)          // 4096 rows
#define NBH  (BB*NHH)         // 24
#define ROWS_BH (NBH*SS)      // 49152
#define NSPLIT 2

typedef unsigned short u16;
typedef unsigned int   u32;
typedef __attribute__((ext_vector_type(8))) short bf16x8_t;   // 8 bf16 (4 VGPRs) - MFMA A/B frag
typedef __attribute__((ext_vector_type(4))) float f32x4;      // MFMA C/D frag
typedef __attribute__((ext_vector_type(2))) u32   u32x2;
typedef __attribute__((ext_vector_type(4))) u32   u32x4;

#define MFMA16(a, b, c) __builtin_amdgcn_mfma_f32_16x16x32_bf16((a), (b), (c), 0, 0, 0)

__device__ __forceinline__ float b2f(u16 u) {
    u32 x = ((u32)u) << 16; float f; __builtin_memcpy(&f, &x, 4); return f;
}
__device__ __forceinline__ u16 f2b(float f) {   // round-to-nearest-even bf16
    u32 x; __builtin_memcpy(&x, &f, 4);
    u32 r = x + 0x7fffu + ((x >> 16) & 1u);
    return (u16)(r >> 16);
}
// async global->LDS 16B DMA (m97 pattern; LDS dest = wave base + lane*16)
__device__ __forceinline__ void async16(const u16* g, u16* l) {
    __builtin_amdgcn_global_load_lds(
        (const __attribute__((address_space(1))) void*)g,
        (__attribute__((address_space(3))) void*)l, 16, 0, 0);
}

// ---------------------------------------------------------------------------
// Kernel 1 (fused prep): blockIdx.x ranges select role.
//   [0,576)      : transpose fp32 768x768 weights -> bf16 Wt[n][k]
//   [576,2624)   : LayerNorm(hidden)->xln (y=0) / cross fp32->bf16 (y=1)
//   [2624,3648)  : maskpack int32->bitmask + per-row window bits (wrow)
// ---------------------------------------------------------------------------
__global__ __launch_bounds__(256) void prep_kernel(
    const float* __restrict__ Wq, const float* __restrict__ Wk,
    const float* __restrict__ Wv, const float* __restrict__ Wo,
    u16* __restrict__ Wt,
    const float* __restrict__ hid, const float* __restrict__ cross,
    const float* __restrict__ g, const float* __restrict__ bb,
    u16* __restrict__ xln, u16* __restrict__ crossb,
    const int* __restrict__ mask, u32* __restrict__ bits,
    u32* __restrict__ wrow)
{
    int id = blockIdx.x;
    int t = threadIdx.x;

    if (id < 576) {
        int mat = id / 144, rem = id % 144;
        int by = rem / 12, bx = rem % 12;
        const float* src = (mat == 0) ? Wq : (mat == 1) ? Wk : (mat == 2) ? Wv : Wo;
        u16* dst = Wt + (size_t)mat * 768 * 768;

        __shared__ float sm[64][68];  // +4 pad
        int r0 = by * 64, c0 = bx * 64;
        #pragma unroll
        for (int it = 0; it < 4; ++it) {
            int c = t + it * 256;
            int r = c >> 4, sg = c & 15;
            *(float4*)&sm[r][sg * 4] = *(const float4*)&src[(size_t)(r0 + r) * 768 + c0 + sg * 4];
        }
        __syncthreads();
        #pragma unroll
        for (int it = 0; it < 2; ++it) {
            int c = t + it * 256;
            int rr = c >> 3, sg = c & 7;
            u16 tmp[8] __attribute__((aligned(16)));
            #pragma unroll
            for (int j = 0; j < 8; ++j) tmp[j] = f2b(sm[sg * 8 + j][rr]);
            *(u32x4*)&dst[(size_t)(c0 + rr) * 768 + r0 + sg * 8] = *(u32x4*)tmp;
        }
        return;
    }

    if (id < 2624) {
        int lid = id - 576;
        int y = lid >> 10, bx = lid & 1023;
        int wv = t >> 6, lane = t & 63;
        int row = bx * 4 + wv;

        if (y == 1) {
            const float* xr = cross + (size_t)row * 768;
            u16* o = crossb + (size_t)row * 768;
            #pragma unroll
            for (int c = 0; c < 3; ++c) {
                float4 f = *(const float4*)&xr[c * 256 + lane * 4];
                u16 t4[4] __attribute__((aligned(8)));
                t4[0] = f2b(f.x); t4[1] = f2b(f.y); t4[2] = f2b(f.z); t4[3] = f2b(f.w);
                *(u32x2*)&o[c * 256 + lane * 4] = *(u32x2*)t4;
            }
            return;
        }

        const float* xr = hid + (size_t)row * 768;
        float v[12];
        float s = 0.f, s2 = 0.f;
        #pragma unroll
        for (int c = 0; c < 3; ++c) {
            float4 f = *(const float4*)&xr[c * 256 + lane * 4];
            v[c*4+0] = f.x; v[c*4+1] = f.y; v[c*4+2] = f.z; v[c*4+3] = f.w;
            s  += f.x + f.y + f.z + f.w;
            s2 += f.x*f.x + f.y*f.y + f.z*f.z + f.w*f.w;
        }
        #pragma unroll
        for (int off = 1; off < 64; off <<= 1) {
            s  += __shfl_xor(s,  off, 64);
            s2 += __shfl_xor(s2, off, 64);
        }
        float mu  = s  * (1.f / 768.f);
        float var = s2 * (1.f / 768.f) - mu * mu;
        float rs  = 1.f / sqrtf(var + 1e-5f);
        #pragma unroll
        for (int c = 0; c < 3; ++c) {
            float4 gg = *(const float4*)&g [c * 256 + lane * 4];
            float4 bv = *(const float4*)&bb[c * 256 + lane * 4];
            u16 o[4] __attribute__((aligned(8)));
            o[0] = f2b((v[c*4+0] - mu) * rs * gg.x + bv.x);
            o[1] = f2b((v[c*4+1] - mu) * rs * gg.y + bv.y);
            o[2] = f2b((v[c*4+2] - mu) * rs * gg.z + bv.z);
            o[3] = f2b((v[c*4+3] - mu) * rs * gg.w + bv.w);
            *(u32x2*)&xln[(size_t)row * 768 + c * 256 + lane * 4] = *(u32x2*)o;
        }
        return;
    }

    {
        int mid = id - 2624;                    // 0..1023
        int w = mid * 256 + t;                  // word index; row = w>>6
        const int4* p = (const int4*)(mask + (size_t)w * 32);
        u32 v = 0;
        #pragma unroll
        for (int i = 0; i < 8; ++i) {
            int4 m = p[i];
            v |= ((m.x != 0) ? 1u : 0u) << (4 * i + 0);
            v |= ((m.y != 0) ? 1u : 0u) << (4 * i + 1);
            v |= ((m.z != 0) ? 1u : 0u) << (4 * i + 2);
            v |= ((m.w != 0) ? 1u : 0u) << (4 * i + 3);
        }
        bits[w] = v;
        unsigned long long ball = __ballot(v == 0xffffffffu);
        if ((t & 63) == 0) {
            u32 wr = 0;
            #pragma unroll
            for (int kt = 0; kt < 32; ++kt)
                if (((ball >> (2 * kt)) & 3ull) == 3ull) wr |= (1u << kt);
            wrow[w >> 6] = wr;
        }
    }
}

// ---------------------------------------------------------------------------
// Shared GEMM mainloop: C[64x128] += A[64xK] * Wt[128xK]^T, BK=64.
// 64x128 tile for occupancy (grid 4.5 blocks/CU, latency-bound regime).
// Single-buffered 24KB LDS; XOR-chunk-swizzled tiles (conflict-free b128).
// ---------------------------------------------------------------------------
__device__ __forceinline__ void gemm64_main(const u16* __restrict__ A,
                                            const u16* __restrict__ W,
                                            f32x4 acc[2][4])
{
    __shared__ __attribute__((aligned(16))) u16 AsL[64 * 64];
    __shared__ __attribute__((aligned(16))) u16 BsL[128 * 64];
    int m0 = blockIdx.x * 64, n0 = blockIdx.y * 128;
    int t = threadIdx.x;
    int wv = t >> 6, lane = t & 63, lm = lane & 15, quad = lane >> 4;
    int wr = wv >> 1, wc = wv & 1;

    for (int kt = 0; kt < 768 / 64; ++kt) {
        __syncthreads();                         // prev-iter reads done
        #pragma unroll
        for (int it = 0; it < 2; ++it) {         // A: 512 chunks, 2/thread
            int c = t + it * 256;
            int row = c >> 3, cs = (c & 7) ^ (row & 7);
            async16(A + (size_t)(m0 + row) * 768 + kt * 64 + cs * 8, &AsL[c * 8]);
        }
        #pragma unroll
        for (int it = 0; it < 4; ++it) {         // B: 1024 chunks, 4/thread
            int c = t + it * 256;
            int row = c >> 3, cs = (c & 7) ^ (row & 7);
            async16(W + (size_t)(n0 + row) * 768 + kt * 64 + cs * 8, &BsL[c * 8]);
        }
        __syncthreads();                         // vmcnt(0) drained by barrier
        #pragma unroll
        for (int kk = 0; kk < 2; ++kk) {
            bf16x8_t af[2], bfv[4];
            #pragma unroll
            for (int i = 0; i < 2; ++i) {
                int r = wr * 32 + i * 16 + lm;
                af[i] = *(const bf16x8_t*)&AsL[(r * 8 + ((kk * 4 + quad) ^ (r & 7))) * 8];
            }
            #pragma unroll
            for (int j = 0; j < 4; ++j) {
                int r = wc * 64 + j * 16 + lm;
                bfv[j] = *(const bf16x8_t*)&BsL[(r * 8 + ((kk * 4 + quad) ^ (r & 7))) * 8];
            }
            #pragma unroll
            for (int i = 0; i < 2; ++i)
                #pragma unroll
                for (int j = 0; j < 4; ++j)
                    acc[i][j] = MFMA16(af[i], bfv[j], acc[i][j]);
        }
    }
}

// ---------------------------------------------------------------------------
// Kernel 2: fused QKV projection. z: 0=Q, 1=K, 2=V. V is written TRANSPOSED
// per (b,h): VtG[(b*12+h)*64 + d][s], so attn stages it with straight copies.
// Grid (64, 6, 3) = 1152 blocks.
// ---------------------------------------------------------------------------
__global__ __launch_bounds__(256) void qkv_gemm(
    const u16* __restrict__ xln, const u16* __restrict__ crossb,
    const u16* __restrict__ Wt,  const float* __restrict__ bq,
    const float* __restrict__ bk, const float* __restrict__ bv,
    const float* __restrict__ mem,
    u16* __restrict__ Qb, u16* __restrict__ Kb, u16* __restrict__ VtG)
{
    int z = blockIdx.z;
    const u16* A      = (z == 0) ? xln : crossb;
    const u16* W      = Wt + (size_t)z * 768 * 768;
    const float* bias = (z == 0) ? bq : (z == 1) ? bk : bv;
    const float* mp   = (z == 0) ? (const float*)nullptr : mem + (size_t)(z - 1) * BSS * HH;

    f32x4 z4 = {0.f, 0.f, 0.f, 0.f};
    f32x4 acc[2][4];
    #pragma unroll
    for (int i = 0; i < 2; ++i)
        #pragma unroll
        for (int j = 0; j < 4; ++j) acc[i][j] = z4;

    gemm64_main(A, W, acc);

    int t = threadIdx.x, wv = t >> 6, lane = t & 63, lm = lane & 15, quad = lane >> 4;
    int wr = wv >> 1, wc = wv & 1;
    int row0 = blockIdx.x * 64 + wr * 32 + quad * 4;   // C/D: row = quad*4+reg
    int col0 = blockIdx.y * 128 + wc * 64 + lm;        //      col = lane&15

    if (z == 2) {
        // V: transposed store, 4 row-consecutive elems -> contiguous s -> 8B
        #pragma unroll
        for (int j = 0; j < 4; ++j) {
            int cg = col0 + j * 16;
            float bz = bias[cg];
            int h = cg >> 6, d = cg & 63;
            #pragma unroll
            for (int i = 0; i < 2; ++i) {
                int rg = row0 + i * 16;
                int b = rg >> 11, s = rg & 2047;
                u16 ob[4] __attribute__((aligned(8)));
                #pragma unroll
                for (int e = 0; e < 4; ++e) {
                    float v = acc[i][j][e] + bz + 0.5f * mp[(size_t)(rg + e) * HH + cg];
                    ob[e] = f2b(v);
                }
                *(u32x2*)&VtG[((size_t)(b * NHH + h) * 64 + d) * SS + s] = *(u32x2*)ob;
            }
        }
        return;
    }

    u16* out = (z == 0) ? Qb : Kb;
    #pragma unroll
    for (int j = 0; j < 4; ++j) {
        int cg = col0 + j * 16;
        float bz = bias[cg];
        #pragma unroll
        for (int i = 0; i < 2; ++i) {
            int rg = row0 + i * 16;
            #pragma unroll
            for (int e = 0; e < 4; ++e) {
                float v = acc[i][j][e] + bz;
                if (mp) v += 0.5f * mp[(size_t)(rg + e) * HH + cg];
                out[(size_t)(rg + e) * HH + cg] = f2b(v);
            }
        }
    }
}

// ---------------------------------------------------------------------------
// Kernel 3: flash attention v3 — LDS-traffic-bound fix.
// 4 waves x 32 q-rows (two 16-row groups/wave): K and V LDS fragment reads
// are issued ONCE per wave and feed BOTH q-groups' MFMAs -> LDS bytes per
// MFMA drop from 1.15KB to 0.77KB and total LDS read traffic falls ~44%
// (half the waves, same per-wave reads). Block still 128 q-rows -> grid 768
// = 3 blocks/CU; LDS 51.2KB unchanged; double-buffered K/V staging kept.
// __launch_bounds__(256,3) keeps 12 waves/CU resident (VGPR cap ~170).
// ---------------------------------------------------------------------------
__global__ __launch_bounds__(256, 3) void attn_kernel(
    const u16* __restrict__ Q, const u16* __restrict__ K,
    const u16* __restrict__ VtG, const u32* __restrict__ mbits,
    const u32* __restrict__ wrow,
    u16* __restrict__ Pacc, float* __restrict__ Pl, int ksteps)
{
    __shared__ __attribute__((aligned(16))) u16   KsL[2][64 * 64];
    __shared__ __attribute__((aligned(16))) u16   VtL[2][64 * 64];
    __shared__ __attribute__((aligned(16))) short Ps[4][32][72];

    int qt = blockIdx.x;             // 0..15 q-tiles (128 rows each)
    int bh = blockIdx.y;             // 0..23
    int z  = blockIdx.z;             // split index
    int b = bh / NHH, h = bh % NHH;
    int t = threadIdx.x;
    int wv = t >> 6, lane = t & 63, lm = lane & 15, quad = lane >> 4;
    int r7 = lm & 7;

    // wave's 32 q-rows: group0 = qrow0..+15, group1 = qrow0+16..+31
    int qrow0 = b * SS + qt * 128 + wv * 32;
    const u16* qp0 = Q + (size_t)(qrow0 + lm) * HH + h * 64;
    const u16* qp1 = Q + (size_t)(qrow0 + 16 + lm) * HH + h * 64;
    bf16x8_t qa0 = *(const bf16x8_t*)&qp0[quad * 8];
    bf16x8_t qa1 = *(const bf16x8_t*)&qp0[32 + quad * 8];
    bf16x8_t qb0 = *(const bf16x8_t*)&qp1[quad * 8];
    bf16x8_t qb1 = *(const bf16x8_t*)&qp1[32 + quad * 8];

    f32x4 z4 = {0.f, 0.f, 0.f, 0.f};
    f32x4 acc0[4] = {z4, z4, z4, z4};
    f32x4 acc1[4] = {z4, z4, z4, z4};
    float l0[4] = {0.f, 0.f, 0.f, 0.f};
    float l1[4] = {0.f, 0.f, 0.f, 0.f};

    const float SC = 0.18033688011112042f;       // log2(e)/sqrt(64)
    int ql0 = qt * 128 + wv * 32 + quad * 4;     // group0 row base (within b)
    int ql1 = ql0 + 16;

    u32 wand0 = wrow[b * SS + ql0 + 0] & wrow[b * SS + ql0 + 1] &
                wrow[b * SS + ql0 + 2] & wrow[b * SS + ql0 + 3];
    u32 wand1 = wrow[b * SS + ql1 + 0] & wrow[b * SS + ql1 + 1] &
                wrow[b * SS + ql1 + 2] & wrow[b * SS + ql1 + 3];
    u32 wandA = wand0 & wand1;

    // staging: 256 threads, 2 chunks each per tile (K and V): 4 async16/thread
    const u16* Kb0 = K + (size_t)(b * SS) * HH + h * 64;
    const u16* Vb0 = VtG + (size_t)bh * 64 * SS;

    auto STAGE = [&](int pp, int kt) {
        int k0 = kt * 64;
        #pragma unroll
        for (int it = 0; it < 2; ++it) {
            int c = t + it * 256;                // 0..511 chunk index
            int kr = c >> 3, cs = (c & 7) ^ (kr & 7);
            async16(Kb0 + (size_t)(k0 + kr) * HH + cs * 8, &KsL[pp][c * 8]);
            async16(Vb0 + (size_t)kr * SS + k0 + cs * 8,   &VtL[pp][c * 8]);
        }
    };

    int kt0 = z * ksteps, ktE = kt0 + ksteps;
    STAGE(0, kt0);
    __syncthreads();                 // prologue tile resident

    for (int kt = kt0; kt < ktE; ++kt) {
        int p = (kt - kt0) & 1;
        if (kt + 1 < ktE) STAGE(p ^ 1, kt + 1);   // prefetch next tile

        // scores: 32(q) x 64(k) per wave; K frags read once, used twice
        f32x4 sc0[4], sc1[4];
        #pragma unroll
        for (int k16 = 0; k16 < 4; ++k16) {
            int rowk = k16 * 16 + lm;
            bf16x8_t kf0 = *(const bf16x8_t*)&KsL[p][(rowk * 8 + (quad ^ r7)) * 8];
            bf16x8_t kf1 = *(const bf16x8_t*)&KsL[p][(rowk * 8 + ((quad ^ 4) ^ r7)) * 8];
            f32x4 a0 = z4, a1 = z4;
            a0 = MFMA16(qa0, kf0, a0);
            a1 = MFMA16(qb0, kf0, a1);
            a0 = MFMA16(qa1, kf1, a0);
            a1 = MFMA16(qb1, kf1, a1);
            sc0[k16] = a0;
            sc1[k16] = a1;
        }

        // mask slow path only if some window bit is 0 (either group)
        if (!__all((int)((wandA >> kt) & 1u))) {
            #pragma unroll
            for (int e = 0; e < 4; ++e) {
                u32x2 u0 = *(const u32x2*)&mbits[(size_t)(b * SS + ql0 + e) * (SS / 32) + kt * 2];
                unsigned long long mw0 = ((unsigned long long)u0.y << 32) | (unsigned long long)u0.x;
                u32x2 u1 = *(const u32x2*)&mbits[(size_t)(b * SS + ql1 + e) * (SS / 32) + kt * 2];
                unsigned long long mw1 = ((unsigned long long)u1.y << 32) | (unsigned long long)u1.x;
                #pragma unroll
                for (int k16 = 0; k16 < 4; ++k16) {
                    if (!((mw0 >> (k16 * 16 + lm)) & 1ull)) sc0[k16][e] = -3.0e38f;
                    if (!((mw1 >> (k16 * 16 + lm)) & 1ull)) sc1[k16][e] = -3.0e38f;
                }
            }
        }

        // fixed-max softmax: p = exp2(s*SC); per-lane l partials; P -> LDS
        #pragma unroll
        for (int k16 = 0; k16 < 4; ++k16) {
            int colg = ((k16 + quad) & 3) * 16;
            #pragma unroll
            for (int e = 0; e < 4; ++e) {
                float p0 = __builtin_amdgcn_exp2f(sc0[k16][e] * SC);
                float p1 = __builtin_amdgcn_exp2f(sc1[k16][e] * SC);
                l0[e] += p0;
                l1[e] += p1;
                u32 pb0 = __builtin_bit_cast(u32, p0);
                u32 pb1 = __builtin_bit_cast(u32, p1);
                Ps[wv][quad * 4 + e][colg + lm]      = (short)((pb0 + 0x8000u) >> 16);
                Ps[wv][16 + quad * 4 + e][colg + lm] = (short)((pb1 + 0x8000u) >> 16);
            }
        }
        __asm__ volatile("" ::: "memory");

        // PV: acc[q][d] += P[q][k] * V[k][d]; V frags read once, used twice
        #pragma unroll
        for (int cc = 0; cc < 2; ++cc) {
            int k16r = cc * 2 + (quad >> 1);
            int colg = ((k16r + (lm >> 2)) & 3) * 16 + (quad & 1) * 8;
            bf16x8_t pf0 = *(const bf16x8_t*)&Ps[wv][lm][colg];
            bf16x8_t pf1 = *(const bf16x8_t*)&Ps[wv][16 + lm][colg];
            #pragma unroll
            for (int j = 0; j < 4; ++j) {
                bf16x8_t vf = *(const bf16x8_t*)&VtL[p][((j * 16 + lm) * 8 + ((cc * 4 + quad) ^ r7)) * 8];
                acc0[j] = MFMA16(pf0, vf, acc0[j]);
                acc1[j] = MFMA16(pf1, vf, acc1[j]);
            }
        }

        __syncthreads();   // prefetch landed + all waves done reading buf[p]
    }

    // one-time l reduction across the 16 lanes of the row group
    #pragma unroll
    for (int off = 1; off < 16; off <<= 1) {
        #pragma unroll
        for (int e = 0; e < 4; ++e) {
            l0[e] += __shfl_xor(l0[e], off, 64);
            l1[e] += __shfl_xor(l1[e], off, 64);
        }
    }

    // epilogue: write unnormalized partials for both groups
    size_t prow0 = ((size_t)z * NBH + bh) * SS + qt * 128 + wv * 32 + quad * 4;
    size_t prow1 = prow0 + 16;
    #pragma unroll
    for (int j = 0; j < 4; ++j)
        #pragma unroll
        for (int e = 0; e < 4; ++e) {
            Pacc[(prow0 + e) * 64 + j * 16 + lm] = f2b(acc0[j][e]);
            Pacc[(prow1 + e) * 64 + j * 16 + lm] = f2b(acc1[j][e]);
        }
    if (lm == 0) {
        #pragma unroll
        for (int e = 0; e < 4; ++e) {
            Pl[prow0 + e] = l0[e];
            Pl[prow1 + e] = l1[e];
        }
    }
}

// ---------------------------------------------------------------------------
// Kernel 3b: merge split-K partials -> AO (bf16 [B*S][H] layout).
// ---------------------------------------------------------------------------
__global__ __launch_bounds__(256) void attn_merge(
    const u16* __restrict__ Pacc, const float* __restrict__ Pl,
    u16* __restrict__ AO)
{
    int t = threadIdx.x;
    int r = blockIdx.x * 64 + (t >> 2);          // bh*2048 + q
    int dseg = (t & 3) * 16;

    float lsum = Pl[r] + Pl[(size_t)ROWS_BH + r];

    float o[16];
    #pragma unroll
    for (int i = 0; i < 16; ++i) o[i] = 0.f;
    #pragma unroll
    for (int s = 0; s < NSPLIT; ++s) {
        const u16* ap = &Pacc[((size_t)s * ROWS_BH + r) * 64 + dseg];
        u32x4 a0 = *(const u32x4*)ap;
        u32x4 a1 = *(const u32x4*)(ap + 8);
        u32 wa[8];
        wa[0]=a0.x; wa[1]=a0.y; wa[2]=a0.z; wa[3]=a0.w;
        wa[4]=a1.x; wa[5]=a1.y; wa[6]=a1.z; wa[7]=a1.w;
        #pragma unroll
        for (int i = 0; i < 8; ++i) {
            o[2*i]   += b2f((u16)(wa[i] & 0xffff));
            o[2*i+1] += b2f((u16)(wa[i] >> 16));
        }
    }
    float inv = 1.f / lsum;
    int bh = r >> 11, q = r & 2047;
    int b = bh / NHH, h = bh % NHH;
    u16 ob[16] __attribute__((aligned(16)));
    #pragma unroll
    for (int i = 0; i < 16; ++i) ob[i] = f2b(o[i] * inv);
    u16* op = &AO[((size_t)(b * SS + q)) * HH + h * 64 + dseg];
    *(u32x4*)op       = *(u32x4*)ob;
    *(u32x4*)(op + 8) = *(u32x4*)(ob + 8);
}

// ---------------------------------------------------------------------------
// Kernel 4: output projection + fp32 epilogue, fp32 output.
// Grid (64, 6) = 384 blocks.
// ---------------------------------------------------------------------------
__global__ __launch_bounds__(256) void out_gemm(
    const u16* __restrict__ AO, const u16* __restrict__ Wt,
    const float* __restrict__ bo, const float* __restrict__ gate,
    const float* __restrict__ gbias, const float* __restrict__ dyn,
    float* __restrict__ out)
{
    f32x4 z4 = {0.f, 0.f, 0.f, 0.f};
    f32x4 acc[2][4];
    #pragma unroll
    for (int i = 0; i < 2; ++i)
        #pragma unroll
        for (int j = 0; j < 4; ++j) acc[i][j] = z4;

    gemm64_main(AO, Wt, acc);

    float gv = gate[0];
    float gb = gbias[0];
    int t = threadIdx.x, wv = t >> 6, lane = t & 63, lm = lane & 15, quad = lane >> 4;
    int wr = wv >> 1, wc = wv & 1;
    int row0 = blockIdx.x * 64 + wr * 32 + quad * 4;
    int col0 = blockIdx.y * 128 + wc * 64 + lm;
    #pragma unroll
    for (int j = 0; j < 4; ++j) {
        int cg = col0 + j * 16;
        float bz = bo[cg];
        #pragma unroll
        for (int i = 0; i < 2; ++i) {
            int rg = row0 + i * 16;
            #pragma unroll
            for (int e = 0; e < 4; ++e) {
                float v = acc[i][j][e] + bz;
                v = v * gv + gb;
                v *= dyn[rg + e];
                out[(size_t)(rg + e) * HH + cg] = v;
            }
        }
    }
}

// ---------------------------------------------------------------------------
extern "C" void kernel_launch(void* const* d_in, const int* in_sizes, int n_in,
                              void* d_out, int out_size, void* d_ws, size_t ws_size,
                              hipStream_t stream)
{
    (void)in_sizes; (void)n_in; (void)out_size; (void)ws_size;

    const float* hid   = (const float*)d_in[0];
    const float* cross = (const float*)d_in[1];
    const int*   amask = (const int*)d_in[2];
    const float* mem   = (const float*)d_in[3];
    const float* dyn   = (const float*)d_in[4];
    const float* Wq    = (const float*)d_in[5];
    const float* bq    = (const float*)d_in[6];
    const float* Wk    = (const float*)d_in[7];
    const float* bk    = (const float*)d_in[8];
    const float* Wv    = (const float*)d_in[9];
    const float* bv    = (const float*)d_in[10];
    const float* Wo    = (const float*)d_in[11];
    const float* bo    = (const float*)d_in[12];
    const float* gate  = (const float*)d_in[13];
    const float* gbias = (const float*)d_in[14];
    const float* lng   = (const float*)d_in[15];
    const float* lnb   = (const float*)d_in[16];

    // workspace layout (37.3 MB, proven footprint):
    //   Pacc (12.58 MB) overlays xln+crb (dead after qkv_gemm)
    //   Pl (393 KB) overlays Wt[0]=Wq^T (dead after qkv_gemm)
    //   AO overlays Kb (dead after attn)
    char* p = (char*)d_ws;
    u16* Wt   = (u16*)p; p += (size_t)4 * 768 * 768 * 2;        // 4.72 MB
    u32* mb   = (u32*)p; p += (size_t)BB * SS * (SS / 32) * 4;  // 1.05 MB
    u32* wrow = (u32*)p; p += (size_t)BSS * 4;                  // 16 KB
    u16* xln  = (u16*)p; p += (size_t)BSS * HH * 2;             // 6.29 MB
    u16* crb  = (u16*)p; p += (size_t)BSS * HH * 2;             // 6.29 MB
    u16* Qb   = (u16*)p; p += (size_t)BSS * HH * 2;
    u16* Kb   = (u16*)p; p += (size_t)BSS * HH * 2;
    u16* VtG  = (u16*)p; p += (size_t)BSS * HH * 2;             // V transposed [bh][d][s]
    u16* Pacc  = xln;            // 2 x 24 x 2048 x 64 bf16 = 12.58 MB
    float* Pl  = (float*)Wt;     // 2 x 49152 fp32 = 393 KB (< Wq^T's 1.18 MB)
    u16* AO    = Kb;

    prep_kernel <<<dim3(3648),           256, 0, stream>>>(
        Wq, Wk, Wv, Wo, Wt, hid, cross, lng, lnb, xln, crb, amask, mb, wrow);
    qkv_gemm    <<<dim3(64, 6, 3),       256, 0, stream>>>(
        xln, crb, Wt, bq, bk, bv, mem, Qb, Kb, VtG);
    attn_kernel <<<dim3(16, 24, NSPLIT), 256, 0, stream>>>(
        Qb, Kb, VtG, mb, wrow, Pacc, Pl, SS / 64 / NSPLIT);
    attn_merge  <<<dim3(ROWS_BH / 64),   256, 0, stream>>>(Pacc, Pl, AO);
    out_gemm    <<<dim3(64, 6),          256, 0, stream>>>(
        AO, Wt + (size_t)3 * 768 * 768, bo, gate, gbias, dyn, (float*)d_out);
}

// Round 4
// 238.704 us; speedup vs baseline: 1.0989x; 1.0077x over previous
//
#include <hip/hip_runtime.h>
#include <hip/hip_bf16.h>
#include <stdint.h>

// Problem constants
#define BB   2
#define SS   2048
#define HH   768
#define NHH  12
#define HDD  64
#define BSS  (BB*SS)          // 4096 rows
#define NBH  (BB*NHH)         // 24
#define ROWS_BH (NBH*SS)      // 49152
#define NSPLIT 2

typedef unsigned short u16;
typedef unsigned int   u32;
typedef __attribute__((ext_vector_type(8))) short bf16x8_t;   // 8 bf16 (4 VGPRs) - MFMA A/B frag
typedef __attribute__((ext_vector_type(4))) float f32x4;      // MFMA C/D frag (16x16)
typedef __attribute__((ext_vector_type(16))) float f32x16;    // MFMA C/D frag (32x32)
typedef __attribute__((ext_vector_type(2))) u32   u32x2;
typedef __attribute__((ext_vector_type(4))) u32   u32x4;

#define MFMA16(a, b, c) __builtin_amdgcn_mfma_f32_16x16x32_bf16((a), (b), (c), 0, 0, 0)
#define MFMA32(a, b, c) __builtin_amdgcn_mfma_f32_32x32x16_bf16((a), (b), (c), 0, 0, 0)

__device__ __forceinline__ float b2f(u16 u) {
    u32 x = ((u32)u) << 16; float f; __builtin_memcpy(&f, &x, 4); return f;
}
__device__ __forceinline__ u16 f2b(float f) {   // round-to-nearest-even bf16
    u32 x; __builtin_memcpy(&x, &f, 4);
    u32 r = x + 0x7fffu + ((x >> 16) & 1u);
    return (u16)(r >> 16);
}
// pack two f32 -> one u32 of 2 bf16 (lo = a, hi = b), single instruction
__device__ __forceinline__ u32 cvtpk(float a, float b) {
    u32 r;
    __asm__("v_cvt_pk_bf16_f32 %0, %1, %2" : "=v"(r) : "v"(a), "v"(b));
    return r;
}
// async global->LDS 16B DMA (m97 pattern; LDS dest = wave base + lane*16)
__device__ __forceinline__ void async16(const u16* g, u16* l) {
    __builtin_amdgcn_global_load_lds(
        (const __attribute__((address_space(1))) void*)g,
        (__attribute__((address_space(3))) void*)l, 16, 0, 0);
}

// ---------------------------------------------------------------------------
// Kernel 1 (fused prep): blockIdx.x ranges select role.
//   [0,576)      : transpose fp32 768x768 weights -> bf16 Wt[n][k]
//   [576,2624)   : LayerNorm(hidden)->xln (y=0) / cross fp32->bf16 (y=1)
//   [2624,3648)  : maskpack int32->bitmask + per-row window bits (wrow)
// ---------------------------------------------------------------------------
__global__ __launch_bounds__(256) void prep_kernel(
    const float* __restrict__ Wq, const float* __restrict__ Wk,
    const float* __restrict__ Wv, const float* __restrict__ Wo,
    u16* __restrict__ Wt,
    const float* __restrict__ hid, const float* __restrict__ cross,
    const float* __restrict__ g, const float* __restrict__ bb,
    u16* __restrict__ xln, u16* __restrict__ crossb,
    const int* __restrict__ mask, u32* __restrict__ bits,
    u32* __restrict__ wrow)
{
    int id = blockIdx.x;
    int t = threadIdx.x;

    if (id < 576) {
        int mat = id / 144, rem = id % 144;
        int by = rem / 12, bx = rem % 12;
        const float* src = (mat == 0) ? Wq : (mat == 1) ? Wk : (mat == 2) ? Wv : Wo;
        u16* dst = Wt + (size_t)mat * 768 * 768;

        __shared__ float sm[64][68];  // +4 pad
        int r0 = by * 64, c0 = bx * 64;
        #pragma unroll
        for (int it = 0; it < 4; ++it) {
            int c = t + it * 256;
            int r = c >> 4, sg = c & 15;
            *(float4*)&sm[r][sg * 4] = *(const float4*)&src[(size_t)(r0 + r) * 768 + c0 + sg * 4];
        }
        __syncthreads();
        #pragma unroll
        for (int it = 0; it < 2; ++it) {
            int c = t + it * 256;
            int rr = c >> 3, sg = c & 7;
            u16 tmp[8] __attribute__((aligned(16)));
            #pragma unroll
            for (int j = 0; j < 8; ++j) tmp[j] = f2b(sm[sg * 8 + j][rr]);
            *(u32x4*)&dst[(size_t)(c0 + rr) * 768 + r0 + sg * 8] = *(u32x4*)tmp;
        }
        return;
    }

    if (id < 2624) {
        int lid = id - 576;
        int y = lid >> 10, bx = lid & 1023;
        int wv = t >> 6, lane = t & 63;
        int row = bx * 4 + wv;

        if (y == 1) {
            const float* xr = cross + (size_t)row * 768;
            u16* o = crossb + (size_t)row * 768;
            #pragma unroll
            for (int c = 0; c < 3; ++c) {
                float4 f = *(const float4*)&xr[c * 256 + lane * 4];
                u16 t4[4] __attribute__((aligned(8)));
                t4[0] = f2b(f.x); t4[1] = f2b(f.y); t4[2] = f2b(f.z); t4[3] = f2b(f.w);
                *(u32x2*)&o[c * 256 + lane * 4] = *(u32x2*)t4;
            }
            return;
        }

        const float* xr = hid + (size_t)row * 768;
        float v[12];
        float s = 0.f, s2 = 0.f;
        #pragma unroll
        for (int c = 0; c < 3; ++c) {
            float4 f = *(const float4*)&xr[c * 256 + lane * 4];
            v[c*4+0] = f.x; v[c*4+1] = f.y; v[c*4+2] = f.z; v[c*4+3] = f.w;
            s  += f.x + f.y + f.z + f.w;
            s2 += f.x*f.x + f.y*f.y + f.z*f.z + f.w*f.w;
        }
        #pragma unroll
        for (int off = 1; off < 64; off <<= 1) {
            s  += __shfl_xor(s,  off, 64);
            s2 += __shfl_xor(s2, off, 64);
        }
        float mu  = s  * (1.f / 768.f);
        float var = s2 * (1.f / 768.f) - mu * mu;
        float rs  = 1.f / sqrtf(var + 1e-5f);
        #pragma unroll
        for (int c = 0; c < 3; ++c) {
            float4 gg = *(const float4*)&g [c * 256 + lane * 4];
            float4 bv = *(const float4*)&bb[c * 256 + lane * 4];
            u16 o[4] __attribute__((aligned(8)));
            o[0] = f2b((v[c*4+0] - mu) * rs * gg.x + bv.x);
            o[1] = f2b((v[c*4+1] - mu) * rs * gg.y + bv.y);
            o[2] = f2b((v[c*4+2] - mu) * rs * gg.z + bv.z);
            o[3] = f2b((v[c*4+3] - mu) * rs * gg.w + bv.w);
            *(u32x2*)&xln[(size_t)row * 768 + c * 256 + lane * 4] = *(u32x2*)o;
        }
        return;
    }

    {
        int mid = id - 2624;                    // 0..1023
        int w = mid * 256 + t;                  // word index; row = w>>6
        const int4* p = (const int4*)(mask + (size_t)w * 32);
        u32 v = 0;
        #pragma unroll
        for (int i = 0; i < 8; ++i) {
            int4 m = p[i];
            v |= ((m.x != 0) ? 1u : 0u) << (4 * i + 0);
            v |= ((m.y != 0) ? 1u : 0u) << (4 * i + 1);
            v |= ((m.z != 0) ? 1u : 0u) << (4 * i + 2);
            v |= ((m.w != 0) ? 1u : 0u) << (4 * i + 3);
        }
        bits[w] = v;
        unsigned long long ball = __ballot(v == 0xffffffffu);
        if ((t & 63) == 0) {
            u32 wr = 0;
            #pragma unroll
            for (int kt = 0; kt < 32; ++kt)
                if (((ball >> (2 * kt)) & 3ull) == 3ull) wr |= (1u << kt);
            wrow[w >> 6] = wr;
        }
    }
}

// ---------------------------------------------------------------------------
// Shared GEMM mainloop: C[64x128] += A[64xK] * Wt[128xK]^T, BK=64.
// 64x128 tile for occupancy (grid 4.5 blocks/CU, latency-bound regime).
// Single-buffered 24KB LDS; XOR-chunk-swizzled tiles (conflict-free b128).
// ---------------------------------------------------------------------------
__device__ __forceinline__ void gemm64_main(const u16* __restrict__ A,
                                            const u16* __restrict__ W,
                                            f32x4 acc[2][4])
{
    __shared__ __attribute__((aligned(16))) u16 AsL[64 * 64];
    __shared__ __attribute__((aligned(16))) u16 BsL[128 * 64];
    int m0 = blockIdx.x * 64, n0 = blockIdx.y * 128;
    int t = threadIdx.x;
    int wv = t >> 6, lane = t & 63, lm = lane & 15, quad = lane >> 4;
    int wr = wv >> 1, wc = wv & 1;

    for (int kt = 0; kt < 768 / 64; ++kt) {
        __syncthreads();                         // prev-iter reads done
        #pragma unroll
        for (int it = 0; it < 2; ++it) {         // A: 512 chunks, 2/thread
            int c = t + it * 256;
            int row = c >> 3, cs = (c & 7) ^ (row & 7);
            async16(A + (size_t)(m0 + row) * 768 + kt * 64 + cs * 8, &AsL[c * 8]);
        }
        #pragma unroll
        for (int it = 0; it < 4; ++it) {         // B: 1024 chunks, 4/thread
            int c = t + it * 256;
            int row = c >> 3, cs = (c & 7) ^ (row & 7);
            async16(W + (size_t)(n0 + row) * 768 + kt * 64 + cs * 8, &BsL[c * 8]);
        }
        __syncthreads();                         // vmcnt(0) drained by barrier
        #pragma unroll
        for (int kk = 0; kk < 2; ++kk) {
            bf16x8_t af[2], bfv[4];
            #pragma unroll
            for (int i = 0; i < 2; ++i) {
                int r = wr * 32 + i * 16 + lm;
                af[i] = *(const bf16x8_t*)&AsL[(r * 8 + ((kk * 4 + quad) ^ (r & 7))) * 8];
            }
            #pragma unroll
            for (int j = 0; j < 4; ++j) {
                int r = wc * 64 + j * 16 + lm;
                bfv[j] = *(const bf16x8_t*)&BsL[(r * 8 + ((kk * 4 + quad) ^ (r & 7))) * 8];
            }
            #pragma unroll
            for (int i = 0; i < 2; ++i)
                #pragma unroll
                for (int j = 0; j < 4; ++j)
                    acc[i][j] = MFMA16(af[i], bfv[j], acc[i][j]);
        }
    }
}

// ---------------------------------------------------------------------------
// Kernel 2: fused QKV projection. z: 0=Q, 1=K, 2=V. V is written TRANSPOSED
// per (b,h): VtG[(b*12+h)*64 + d][s], so attn stages it with straight copies.
// Grid (64, 6, 3) = 1152 blocks.
// ---------------------------------------------------------------------------
__global__ __launch_bounds__(256) void qkv_gemm(
    const u16* __restrict__ xln, const u16* __restrict__ crossb,
    const u16* __restrict__ Wt,  const float* __restrict__ bq,
    const float* __restrict__ bk, const float* __restrict__ bv,
    const float* __restrict__ mem,
    u16* __restrict__ Qb, u16* __restrict__ Kb, u16* __restrict__ VtG)
{
    int z = blockIdx.z;
    const u16* A      = (z == 0) ? xln : crossb;
    const u16* W      = Wt + (size_t)z * 768 * 768;
    const float* bias = (z == 0) ? bq : (z == 1) ? bk : bv;
    const float* mp   = (z == 0) ? (const float*)nullptr : mem + (size_t)(z - 1) * BSS * HH;

    f32x4 z4 = {0.f, 0.f, 0.f, 0.f};
    f32x4 acc[2][4];
    #pragma unroll
    for (int i = 0; i < 2; ++i)
        #pragma unroll
        for (int j = 0; j < 4; ++j) acc[i][j] = z4;

    gemm64_main(A, W, acc);

    int t = threadIdx.x, wv = t >> 6, lane = t & 63, lm = lane & 15, quad = lane >> 4;
    int wr = wv >> 1, wc = wv & 1;
    int row0 = blockIdx.x * 64 + wr * 32 + quad * 4;   // C/D: row = quad*4+reg
    int col0 = blockIdx.y * 128 + wc * 64 + lm;        //      col = lane&15

    if (z == 2) {
        // V: transposed store, 4 row-consecutive elems -> contiguous s -> 8B
        #pragma unroll
        for (int j = 0; j < 4; ++j) {
            int cg = col0 + j * 16;
            float bz = bias[cg];
            int h = cg >> 6, d = cg & 63;
            #pragma unroll
            for (int i = 0; i < 2; ++i) {
                int rg = row0 + i * 16;
                int b = rg >> 11, s = rg & 2047;
                u16 ob[4] __attribute__((aligned(8)));
                #pragma unroll
                for (int e = 0; e < 4; ++e) {
                    float v = acc[i][j][e] + bz + 0.5f * mp[(size_t)(rg + e) * HH + cg];
                    ob[e] = f2b(v);
                }
                *(u32x2*)&VtG[((size_t)(b * NHH + h) * 64 + d) * SS + s] = *(u32x2*)ob;
            }
        }
        return;
    }

    u16* out = (z == 0) ? Qb : Kb;
    #pragma unroll
    for (int j = 0; j < 4; ++j) {
        int cg = col0 + j * 16;
        float bz = bias[cg];
        #pragma unroll
        for (int i = 0; i < 2; ++i) {
            int rg = row0 + i * 16;
            #pragma unroll
            for (int e = 0; e < 4; ++e) {
                float v = acc[i][j][e] + bz;
                if (mp) v += 0.5f * mp[(size_t)(rg + e) * HH + cg];
                out[(size_t)(rg + e) * HH + cg] = f2b(v);
            }
        }
    }
}

// ---------------------------------------------------------------------------
// Kernel 3: flash attention v4 — swapped-QK 32x32 MFMA, in-register softmax.
// T12 pattern: compute mfma_32x32x16(K, Q) so each lane holds P for ONE
// q-row (q = lane&31); softmax + l-sum are lane-local. P -> PV A-frag via
// v_cvt_pk_bf16_f32 (16/thread) + permlane32_swap (8/thread) — the Ps LDS
// round-trip (32 ds_write_b16 + 4 ds_read_b128 per thread per k-step, ~45%
// of the LDS pipe) is GONE. LDS per wave per k-step: 16 b128 reads only.
// 4 waves x 32 q-rows; K/V double-buffer 32KB LDS; grid 768 = 3 blocks/CU.
// 32x32 C/D layout (m74/m101): col=lane&31, row=(reg&3)+8*(reg>>2)+4*(lane>>5).
// ---------------------------------------------------------------------------
__global__ __launch_bounds__(256, 3) void attn_kernel(
    const u16* __restrict__ Q, const u16* __restrict__ K,
    const u16* __restrict__ VtG, const u32* __restrict__ mbits,
    const u32* __restrict__ wrow,
    u16* __restrict__ Pacc, float* __restrict__ Pl, int ksteps)
{
    __shared__ __attribute__((aligned(16))) u16 KsL[2][64 * 64];
    __shared__ __attribute__((aligned(16))) u16 VtL[2][64 * 64];

    int qt = blockIdx.x;             // 0..15 q-tiles (128 rows each)
    int bh = blockIdx.y;             // 0..23
    int z  = blockIdx.z;             // split index
    int b = bh / NHH, h = bh % NHH;
    int t = threadIdx.x;
    int wv = t >> 6, lane = t & 63;
    int q31 = lane & 31, hi = lane >> 5;

    // Q in registers as B-operand frags: lane holds Q[q=qbase+q31][d=step*16+hi*8+j]
    int qbase = qt * 128 + wv * 32;               // within batch b
    const u16* qp = Q + (size_t)(b * SS + qbase + q31) * HH + h * 64 + hi * 8;
    bf16x8_t qf0 = *(const bf16x8_t*)&qp[0];
    bf16x8_t qf1 = *(const bf16x8_t*)&qp[16];
    bf16x8_t qf2 = *(const bf16x8_t*)&qp[32];
    bf16x8_t qf3 = *(const bf16x8_t*)&qp[48];

    f32x16 acc0 = {};                             // D[q][d], dblk 0 (d 0..31)
    f32x16 acc1 = {};                             // dblk 1 (d 32..63)
    float l_lane = 0.f;

    const float SC = 0.18033688011112042f;        // log2(e)/sqrt(64)

    // per-lane window bits for q-row qbase+q31
    u32 wl = wrow[b * SS + qbase + q31];
    const u32* mrow = &mbits[(size_t)(b * SS + qbase + q31) * (SS / 32)];

    // staging: 256 threads, 2 chunks each per tile (K and V): 4 async16/thread
    int kr = t >> 3, cs = (t & 7) ^ (kr & 7);
    const u16* Kb0 = K + (size_t)(b * SS) * HH + h * 64;
    const u16* Vb0 = VtG + (size_t)bh * 64 * SS;

    auto STAGE = [&](int pp, int kt) {
        int k0 = kt * 64;
        #pragma unroll
        for (int it = 0; it < 2; ++it) {
            int c = t + it * 256;                // 0..511 chunk index
            int rr = c >> 3, ss = (c & 7) ^ (rr & 7);
            async16(Kb0 + (size_t)(k0 + rr) * HH + ss * 8, &KsL[pp][c * 8]);
            async16(Vb0 + (size_t)rr * SS + k0 + ss * 8,   &VtL[pp][c * 8]);
        }
    };
    (void)kr; (void)cs;

    int kt0 = z * ksteps, ktE = kt0 + ksteps;
    STAGE(0, kt0);
    __syncthreads();                 // prologue tile resident

    for (int kt = kt0; kt < ktE; ++kt) {
        int p = (kt - kt0) & 1;
        if (kt + 1 < ktE) STAGE(p ^ 1, kt + 1);   // prefetch next tile

        bool ok = __all((int)((wl >> kt) & 1u));  // tile fully unmasked?
        unsigned long long mw = ~0ull;
        if (!ok) {
            u32x2 u = *(const u32x2*)&mrow[kt * 2];
            mw = ((unsigned long long)u.y << 32) | (unsigned long long)u.x;
        }

        #pragma unroll
        for (int kb = 0; kb < 2; ++kb) {
            // QK^T swapped: sc = K[32k x 64d] . Q[64d x 32q]; lane: q=q31,
            // krow(reg r) = kb*32 + (r&3) + 8*(r>>2) + 4*hi
            f32x16 sc = {};
            #pragma unroll
            for (int step = 0; step < 4; ++step) {
                int row = kb * 32 + q31;
                int ch = (step * 2 + hi) ^ (row & 7);
                bf16x8_t kf = *(const bf16x8_t*)&KsL[p][(row * 8 + ch) * 8];
                bf16x8_t qf = (step == 0) ? qf0 : (step == 1) ? qf1 : (step == 2) ? qf2 : qf3;
                sc = MFMA32(kf, qf, sc);
            }

            // softmax (fixed-max): p = exp2(s*SC); mask -> 0; lane-local l
            #pragma unroll
            for (int r = 0; r < 16; ++r) {
                float pv = __builtin_amdgcn_exp2f(sc[r] * SC);
                if (!ok) {
                    int kbit = kb * 32 + (r & 3) + 8 * (r >> 2) + 4 * hi;
                    if (!((mw >> kbit) & 1ull)) pv = 0.f;
                }
                sc[r] = pv;
                l_lane += pv;
            }

            // P -> A-frag in-register: per 16-k slice s2, pack pairs and
            // permlane32_swap the complementary halves (lane l <-> l+32).
            #pragma unroll
            for (int s2 = 0; s2 < 2; ++s2) {
                u32 P0 = cvtpk(sc[8 * s2 + 0], sc[8 * s2 + 1]);
                u32 P1 = cvtpk(sc[8 * s2 + 2], sc[8 * s2 + 3]);
                u32 P2 = cvtpk(sc[8 * s2 + 4], sc[8 * s2 + 5]);
                u32 P3 = cvtpk(sc[8 * s2 + 6], sc[8 * s2 + 7]);
                auto s02 = __builtin_amdgcn_permlane32_swap((int)P0, (int)P2, false, false);
                auto s13 = __builtin_amdgcn_permlane32_swap((int)P1, (int)P3, false, false);
                u32x4 w;
                w.x = (u32)s02[0]; w.y = (u32)s13[0];
                w.z = (u32)s02[1]; w.w = (u32)s13[1];
                bf16x8_t pf = __builtin_bit_cast(bf16x8_t, w);

                // PV: acc[q][d] += P[q][k16] * V[k16][d]
                int vrow0 = q31;            // dblk 0
                int vrow1 = 32 + q31;       // dblk 1
                int ch = kb * 4 + s2 * 2 + hi;
                bf16x8_t vf0 = *(const bf16x8_t*)&VtL[p][(vrow0 * 8 + (ch ^ (vrow0 & 7))) * 8];
                bf16x8_t vf1 = *(const bf16x8_t*)&VtL[p][(vrow1 * 8 + (ch ^ (vrow1 & 7))) * 8];
                acc0 = MFMA32(pf, vf0, acc0);
                acc1 = MFMA32(pf, vf1, acc1);
            }
        }

        __syncthreads();   // prefetch landed + all waves done reading buf[p]
    }

    // l: lane pairs (l, l+32) share q and hold disjoint k's
    l_lane += __shfl_xor(l_lane, 32, 64);

    // epilogue: write unnormalized partials. acc: col d = dblk*32 + q31,
    // row q = (r&3) + 8*(r>>2) + 4*hi
    size_t prow0 = ((size_t)z * NBH + bh) * SS + qt * 128 + wv * 32;
    #pragma unroll
    for (int r = 0; r < 16; ++r) {
        int qrow = (r & 3) + 8 * (r >> 2) + 4 * hi;
        Pacc[(prow0 + qrow) * 64 + q31]      = f2b(acc0[r]);
        Pacc[(prow0 + qrow) * 64 + 32 + q31] = f2b(acc1[r]);
    }
    if (lane < 32) Pl[prow0 + lane] = l_lane;
}

// ---------------------------------------------------------------------------
// Kernel 3b: merge split-K partials -> AO (bf16 [B*S][H] layout).
// ---------------------------------------------------------------------------
__global__ __launch_bounds__(256) void attn_merge(
    const u16* __restrict__ Pacc, const float* __restrict__ Pl,
    u16* __restrict__ AO)
{
    int t = threadIdx.x;
    int r = blockIdx.x * 64 + (t >> 2);          // bh*2048 + q
    int dseg = (t & 3) * 16;

    float lsum = Pl[r] + Pl[(size_t)ROWS_BH + r];

    float o[16];
    #pragma unroll
    for (int i = 0; i < 16; ++i) o[i] = 0.f;
    #pragma unroll
    for (int s = 0; s < NSPLIT; ++s) {
        const u16* ap = &Pacc[((size_t)s * ROWS_BH + r) * 64 + dseg];
        u32x4 a0 = *(const u32x4*)ap;
        u32x4 a1 = *(const u32x4*)(ap + 8);
        u32 wa[8];
        wa[0]=a0.x; wa[1]=a0.y; wa[2]=a0.z; wa[3]=a0.w;
        wa[4]=a1.x; wa[5]=a1.y; wa[6]=a1.z; wa[7]=a1.w;
        #pragma unroll
        for (int i = 0; i < 8; ++i) {
            o[2*i]   += b2f((u16)(wa[i] & 0xffff));
            o[2*i+1] += b2f((u16)(wa[i] >> 16));
        }
    }
    float inv = 1.f / lsum;
    int bh = r >> 11, q = r & 2047;
    int b = bh / NHH, h = bh % NHH;
    u16 ob[16] __attribute__((aligned(16)));
    #pragma unroll
    for (int i = 0; i < 16; ++i) ob[i] = f2b(o[i] * inv);
    u16* op = &AO[((size_t)(b * SS + q)) * HH + h * 64 + dseg];
    *(u32x4*)op       = *(u32x4*)ob;
    *(u32x4*)(op + 8) = *(u32x4*)(ob + 8);
}

// ---------------------------------------------------------------------------
// Kernel 4: output projection + fp32 epilogue, fp32 output.
// Grid (64, 6) = 384 blocks.
// ---------------------------------------------------------------------------
__global__ __launch_bounds__(256) void out_gemm(
    const u16* __restrict__ AO, const u16* __restrict__ Wt,
    const float* __restrict__ bo, const float* __restrict__ gate,
    const float* __restrict__ gbias, const float* __restrict__ dyn,
    float* __restrict__ out)
{
    f32x4 z4 = {0.f, 0.f, 0.f, 0.f};
    f32x4 acc[2][4];
    #pragma unroll
    for (int i = 0; i < 2; ++i)
        #pragma unroll
        for (int j = 0; j < 4; ++j) acc[i][j] = z4;

    gemm64_main(AO, Wt, acc);

    float gv = gate[0];
    float gb = gbias[0];
    int t = threadIdx.x, wv = t >> 6, lane = t & 63, lm = lane & 15, quad = lane >> 4;
    int wr = wv >> 1, wc = wv & 1;
    int row0 = blockIdx.x * 64 + wr * 32 + quad * 4;
    int col0 = blockIdx.y * 128 + wc * 64 + lm;
    #pragma unroll
    for (int j = 0; j < 4; ++j) {
        int cg = col0 + j * 16;
        float bz = bo[cg];
        #pragma unroll
        for (int i = 0; i < 2; ++i) {
            int rg = row0 + i * 16;
            #pragma unroll
            for (int e = 0; e < 4; ++e) {
                float v = acc[i][j][e] + bz;
                v = v * gv + gb;
                v *= dyn[rg + e];
                out[(size_t)(rg + e) * HH + cg] = v;
            }
        }
    }
}

// ---------------------------------------------------------------------------
extern "C" void kernel_launch(void* const* d_in, const int* in_sizes, int n_in,
                              void* d_out, int out_size, void* d_ws, size_t ws_size,
                              hipStream_t stream)
{
    (void)in_sizes; (void)n_in; (void)out_size; (void)ws_size;

    const float* hid   = (const float*)d_in[0];
    const float* cross = (const float*)d_in[1];
    const int*   amask = (const int*)d_in[2];
    const float* mem   = (const float*)d_in[3];
    const float* dyn   = (const float*)d_in[4];
    const float* Wq    = (const float*)d_in[5];
    const float* bq    = (const float*)d_in[6];
    const float* Wk    = (const float*)d_in[7];
    const float* bk    = (const float*)d_in[8];
    const float* Wv    = (const float*)d_in[9];
    const float* bv    = (const float*)d_in[10];
    const float* Wo    = (const float*)d_in[11];
    const float* bo    = (const float*)d_in[12];
    const float* gate  = (const float*)d_in[13];
    const float* gbias = (const float*)d_in[14];
    const float* lng   = (const float*)d_in[15];
    const float* lnb   = (const float*)d_in[16];

    // workspace layout (37.3 MB, proven footprint):
    //   Pacc (12.58 MB) overlays xln+crb (dead after qkv_gemm)
    //   Pl (393 KB) overlays Wt[0]=Wq^T (dead after qkv_gemm)
    //   AO overlays Kb (dead after attn)
    char* p = (char*)d_ws;
    u16* Wt   = (u16*)p; p += (size_t)4 * 768 * 768 * 2;        // 4.72 MB
    u32* mb   = (u32*)p; p += (size_t)BB * SS * (SS / 32) * 4;  // 1.05 MB
    u32* wrow = (u32*)p; p += (size_t)BSS * 4;                  // 16 KB
    u16* xln  = (u16*)p; p += (size_t)BSS * HH * 2;             // 6.29 MB
    u16* crb  = (u16*)p; p += (size_t)BSS * HH * 2;             // 6.29 MB
    u16* Qb   = (u16*)p; p += (size_t)BSS * HH * 2;
    u16* Kb   = (u16*)p; p += (size_t)BSS * HH * 2;
    u16* VtG  = (u16*)p; p += (size_t)BSS * HH * 2;             // V transposed [bh][d][s]
    u16* Pacc  = xln;            // 2 x 24 x 2048 x 64 bf16 = 12.58 MB
    float* Pl  = (float*)Wt;     // 2 x 49152 fp32 = 393 KB (< Wq^T's 1.18 MB)
    u16* AO    = Kb;

    prep_kernel <<<dim3(3648),           256, 0, stream>>>(
        Wq, Wk, Wv, Wo, Wt, hid, cross, lng, lnb, xln, crb, amask, mb, wrow);
    qkv_gemm    <<<dim3(64, 6, 3),       256, 0, stream>>>(
        xln, crb, Wt, bq, bk, bv, mem, Qb, Kb, VtG);
    attn_kernel <<<dim3(16, 24, NSPLIT), 256, 0, stream>>>(
        Qb, Kb, VtG, mb, wrow, Pacc, Pl, SS / 64 / NSPLIT);
    attn_merge  <<<dim3(ROWS_BH / 64),   256, 0, stream>>>(Pacc, Pl, AO);
    out_gemm    <<<dim3(64, 6),          256, 0, stream>>>(
        AO, Wt + (size_t)3 * 768 * 768, bo, gate, gbias, dyn, (float*)d_out);
}